// Round 1
// baseline (262.656 us; speedup 1.0000x reference)
//
#include <hip/hip_runtime.h>
#include <math.h>

#define BB 2
#define CC 64
#define NN 4096
#define MM 256
#define KK 32
#define GG 4
#define EPSF 1e-5f

__device__ __forceinline__ float gelu_exact(float x) {
    return 0.5f * x * (1.0f + erff(x * 0.70710678118654752f));
}

// ---------------- init: zero the 48 stat doubles ----------------
__global__ void k_init(double* st) {
    int t = threadIdx.x;
    if (t < 48) st[t] = 0.0;
}

// ---------------- mlp1: h = w1 @ x + b1, accumulate stats1 ----------------
// grid 2048 = B * M * (N/1024), block 256, each thread 4 n's
__global__ void k_mlp1(const float* __restrict__ x, const float* __restrict__ w1,
                       const float* __restrict__ b1, float* __restrict__ h, double* st1) {
    int nt = blockIdx.x & 3;
    int i  = (blockIdx.x >> 2) & 255;
    int b  = blockIdx.x >> 10;
    int n0 = nt * 1024;
    int t  = threadIdx.x;

    const float* xb = x + b * CC * NN;
    const float* wr = w1 + i * CC;

    float a0 = 0.f, a1 = 0.f, a2 = 0.f, a3 = 0.f;
    for (int c = 0; c < CC; c++) {
        float wv = wr[c];
        const float* xr = xb + c * NN + n0 + t;
        a0 = fmaf(wv, xr[0],   a0);
        a1 = fmaf(wv, xr[256], a1);
        a2 = fmaf(wv, xr[512], a2);
        a3 = fmaf(wv, xr[768], a3);
    }
    float bv = b1[i];
    a0 += bv; a1 += bv; a2 += bv; a3 += bv;
    float* hr = h + (b * MM + i) * NN + n0 + t;
    hr[0] = a0; hr[256] = a1; hr[512] = a2; hr[768] = a3;

    float s1 = a0 + a1 + a2 + a3;
    float s2 = a0*a0 + a1*a1 + a2*a2 + a3*a3;
    // block reduce
    for (int off = 32; off; off >>= 1) {
        s1 += __shfl_down(s1, off, 64);
        s2 += __shfl_down(s2, off, 64);
    }
    __shared__ float r1[4], r2[4];
    int w = t >> 6, l = t & 63;
    if (l == 0) { r1[w] = s1; r2[w] = s2; }
    __syncthreads();
    if (t == 0) {
        float ts1 = r1[0] + r1[1] + r1[2] + r1[3];
        float ts2 = r2[0] + r2[1] + r2[2] + r2[3];
        int g = i >> 6;
        atomicAdd(&st1[(b * GG + g) * 2 + 0], (double)ts1);
        atomicAdd(&st1[(b * GG + g) * 2 + 1], (double)ts2);
    }
}

// ---------------- gn1 + gelu + wd, transpose to p[b][n][m] ----------------
// grid (N/64, M/64, B), block 256
__global__ void k_gn1t(const float* __restrict__ h, const float* __restrict__ g1,
                       const float* __restrict__ be1, const float* __restrict__ wd,
                       const double* __restrict__ st1, float* __restrict__ p) {
    int n0 = blockIdx.x * 64;
    int m0 = blockIdx.y * 64;
    int b  = blockIdx.z;
    int g  = m0 >> 6;
    double s1 = st1[(b * GG + g) * 2 + 0];
    double s2 = st1[(b * GG + g) * 2 + 1];
    const double cnt = 64.0 * 4096.0;
    double mean_d = s1 / cnt;
    double var_d  = s2 / cnt - mean_d * mean_d;
    float mean = (float)mean_d;
    float rstd = rsqrtf((float)var_d + EPSF);

    __shared__ float tile[64][65];
    int t = threadIdx.x;
    int col = t & 63, row4 = t >> 6;
    #pragma unroll
    for (int i = 0; i < 16; i++) {
        int row = row4 + i * 4;
        int m = m0 + row;
        float hv = h[((b * MM) + m) * NN + n0 + col];
        float a = rstd * g1[m];
        float cc2 = be1[m] - mean * a;
        float u = fmaf(hv, a, cc2);
        tile[row][col] = gelu_exact(u) * wd[m];
    }
    __syncthreads();
    #pragma unroll
    for (int i = 0; i < 16; i++) {
        int ny = row4 + i * 4;
        p[((size_t)(b * NN) + (n0 + ny)) * MM + m0 + col] = tile[col][ny];
    }
}

// ---------------- ball query: one wave per query point ----------------
// grid 2048, block 256 (4 waves)
__global__ void k_ballq(const float* __restrict__ pos, int* __restrict__ idx) {
    int wid  = blockIdx.x * 4 + (threadIdx.x >> 6);
    int lane = threadIdx.x & 63;
    int b = wid >> 12;
    int n = wid & 4095;
    const float* px = pos + b * 3 * NN;
    const float* py = px + NN;
    const float* pz = py + NN;
    float qx = px[n], qy = py[n], qz = pz[n];
    float qsq = qx*qx + qy*qy + qz*qz;
    int* row = idx + (b * NN + n) * KK;

    int found = 0;
    int first = -1;
    const float R2 = 0.04f;
    for (int m0 = 0; m0 < NN && found < KK; m0 += 64) {
        int m = m0 + lane;
        float ax = px[m], ay = py[m], az = pz[m];
        float msq = ax*ax + ay*ay + az*az;
        float dot = qx*ax + qy*ay + qz*az;
        float d = qsq + msq - 2.0f * dot;
        bool hit = !(d > R2);
        unsigned long long mask = __ballot(hit);
        if (first < 0 && mask) first = m0 + (__ffsll((long long)mask) - 1);
        unsigned long long lt = (lane == 0) ? 0ULL : (mask & ((1ULL << lane) - 1ULL));
        int posh = __popcll(lt);
        if (hit && (found + posh) < KK) row[found + posh] = m;
        found += __popcll(mask);
        if (found > KK) found = KK;
    }
    if (lane < KK && lane >= found) row[lane] = first;
}

// ---------------- gather: max/min over 32 neighbors + stats2 ----------------
// grid 512 = B*(N/16), block 256 (thread = channel m)
__global__ void k_gather(const float* __restrict__ p, const int* __restrict__ idx,
                         float* __restrict__ pmax, float* __restrict__ pmin, double* st2) {
    int b  = blockIdx.x >> 8;
    int n0 = (blockIdx.x & 255) * 16;
    int t  = threadIdx.x;
    const float* pb = p + (size_t)b * NN * MM;
    float gs1 = 0.f, gs2 = 0.f;
    __shared__ int sidx[KK];
    for (int nn = 0; nn < 16; nn++) {
        int n = n0 + nn;
        __syncthreads();
        if (t < KK) sidx[t] = idx[(b * NN + n) * KK + t];
        __syncthreads();
        float vmax = -INFINITY, vmin = INFINITY, s1 = 0.f, s2 = 0.f;
        #pragma unroll 8
        for (int k = 0; k < KK; k++) {
            float v = pb[(size_t)sidx[k] * MM + t];
            vmax = fmaxf(vmax, v);
            vmin = fminf(vmin, v);
            s1 += v;
            s2 = fmaf(v, v, s2);
        }
        pmax[((size_t)(b * NN) + n) * MM + t] = vmax;
        pmin[((size_t)(b * NN) + n) * MM + t] = vmin;
        gs1 += s1; gs2 += s2;
    }
    for (int off = 32; off; off >>= 1) {
        gs1 += __shfl_down(gs1, off, 64);
        gs2 += __shfl_down(gs2, off, 64);
    }
    if ((t & 63) == 0) {
        int g = t >> 6;
        atomicAdd(&st2[(b * GG + g) * 2 + 0], (double)gs1);
        atomicAdd(&st2[(b * GG + g) * 2 + 1], (double)gs2);
    }
}

// ---------------- mlp2: h2 = gelu(gn2(max)), o = w2 @ h2 + b2, stats3 ----------------
// grid 512 = B*(N/16), block 256
__global__ void k_mlp2(const float* __restrict__ pmax_, const float* __restrict__ pmin_,
                       const float* __restrict__ w2, const float* __restrict__ b2,
                       const float* __restrict__ gd, const float* __restrict__ bed,
                       const double* __restrict__ st2, float* __restrict__ oraw, double* st3) {
    int b  = blockIdx.x >> 8;
    int n0 = (blockIdx.x & 255) * 16;
    int t  = threadIdx.x;

    int g = t >> 6;
    const double cnt2 = 64.0 * 4096.0 * 32.0;
    double mean_d = st2[(b * GG + g) * 2 + 0] / cnt2;
    double var_d  = st2[(b * GG + g) * 2 + 1] / cnt2 - mean_d * mean_d;
    float rstd = rsqrtf((float)var_d + EPSF);
    float gdm = gd[t];
    float a = rstd * gdm;
    float cadd = bed[t] - (float)mean_d * a;
    const float* src = (gdm >= 0.f) ? pmax_ : pmin_;

    int cc = t >> 2, q = t & 3;
    float w[64];
    #pragma unroll
    for (int j = 0; j < 64; j++) w[j] = w2[cc * MM + q * 64 + j];

    __shared__ float sh2[256];
    __shared__ float sred[64][5];
    float so1 = 0.f, so2 = 0.f;

    for (int nn = 0; nn < 16; nn++) {
        int n = n0 + nn;
        float vm = src[((size_t)(b * NN) + n) * MM + t];
        float u = fmaf(vm, a, cadd);
        float h2 = gelu_exact(u);
        __syncthreads();
        sh2[t] = h2;
        __syncthreads();
        float acc = 0.f;
        #pragma unroll
        for (int j = 0; j < 64; j++) acc = fmaf(w[j], sh2[q * 64 + j], acc);
        sred[cc][q] = acc;
        __syncthreads();
        if (t < 64) {
            float o = b2[t] + sred[t][0] + sred[t][1] + sred[t][2] + sred[t][3];
            oraw[((size_t)(b * CC) + t) * NN + n] = o;
            so1 += o;
            so2 = fmaf(o, o, so2);
        }
    }
    if (t < 64) {
        for (int off = 8; off; off >>= 1) {
            so1 += __shfl_down(so1, off, 64);
            so2 += __shfl_down(so2, off, 64);
        }
        if ((t & 15) == 0) {
            int g3 = t >> 4;
            atomicAdd(&st3[(b * GG + g3) * 2 + 0], (double)so1);
            atomicAdd(&st3[(b * GG + g3) * 2 + 1], (double)so2);
        }
    }
}

// ---------------- final: gn3 + residual ----------------
// grid 2048, block 256
__global__ void k_final(const float* __restrict__ oraw, const float* __restrict__ x,
                        const float* __restrict__ g2, const float* __restrict__ be2,
                        const double* __restrict__ st3, float* __restrict__ out) {
    int gid = blockIdx.x * 256 + threadIdx.x;
    int c = (gid >> 12) & 63;
    int b = gid >> 18;
    int g = c >> 4;
    const double cnt = 16.0 * 4096.0;
    double mean_d = st3[(b * GG + g) * 2 + 0] / cnt;
    double var_d  = st3[(b * GG + g) * 2 + 1] / cnt - mean_d * mean_d;
    float rstd = rsqrtf((float)var_d + EPSF);
    float o = oraw[gid];
    out[gid] = (o - (float)mean_d) * rstd * g2[c] + be2[c] + x[gid];
}

// ---------------- launch ----------------
extern "C" void kernel_launch(void* const* d_in, const int* in_sizes, int n_in,
                              void* d_out, int out_size, void* d_ws, size_t ws_size,
                              hipStream_t stream) {
    const float* x   = (const float*)d_in[0];
    const float* pos = (const float*)d_in[1];
    const float* w1  = (const float*)d_in[2];
    const float* b1  = (const float*)d_in[3];
    const float* g1  = (const float*)d_in[4];
    const float* be1 = (const float*)d_in[5];
    const float* wd  = (const float*)d_in[6];
    const float* gd  = (const float*)d_in[7];
    const float* bed = (const float*)d_in[8];
    const float* w2  = (const float*)d_in[9];
    const float* b2  = (const float*)d_in[10];
    const float* g2  = (const float*)d_in[11];
    const float* be2 = (const float*)d_in[12];
    float* out = (float*)d_out;

    // workspace layout (element offsets in floats)
    float* ws = (float*)d_ws;
    const size_t SZ = (size_t)BB * MM * NN;          // 2,097,152
    float* h    = ws;                                // 8 MB
    float* p    = ws + SZ;                           // 8 MB
    float* pmax = ws + 2 * SZ;                       // 8 MB
    float* pmin = ws + 3 * SZ;                       // 8 MB
    float* oraw = ws + 4 * SZ;                       // 2 MB (B*C*N)
    char* after = (char*)(oraw + (size_t)BB * CC * NN);
    int* idx = (int*)after;                          // 1 MB
    double* st = (double*)(after + (size_t)BB * NN * KK * sizeof(int));
    double* st1 = st;
    double* st2 = st + 16;
    double* st3 = st + 32;

    k_init<<<1, 64, 0, stream>>>(st);
    k_mlp1<<<2048, 256, 0, stream>>>(x, w1, b1, h, st1);
    k_gn1t<<<dim3(64, 4, 2), 256, 0, stream>>>(h, g1, be1, wd, st1, p);
    k_ballq<<<2048, 256, 0, stream>>>(pos, idx);
    k_gather<<<512, 256, 0, stream>>>(p, idx, pmax, pmin, st2);
    k_mlp2<<<512, 256, 0, stream>>>(pmax, pmin, w2, b2, gd, bed, st2, oraw, st3);
    k_final<<<2048, 256, 0, stream>>>(oraw, x, g2, be2, st3, out);
}

// Round 2
// 261.230 us; speedup vs baseline: 1.0055x; 1.0055x over previous
//
#include <hip/hip_runtime.h>
#include <math.h>

#define BB 2
#define CC 64
#define NN 4096
#define MM 256
#define KK 32
#define GG 4
#define EPSF 1e-5f

__device__ __forceinline__ float gelu_exact(float x) {
    return 0.5f * x * (1.0f + erff(x * 0.70710678118654752f));
}

// ---------------- init: zero the 48 stat doubles ----------------
__global__ void k_init(double* st) {
    int t = threadIdx.x;
    if (t < 48) st[t] = 0.0;
}

// ---------------- mlp1: h = w1 @ x + b1, accumulate stats1 ----------------
// grid 2048 = B * M * (N/1024), block 256, each thread 4 n's
__global__ void k_mlp1(const float* __restrict__ x, const float* __restrict__ w1,
                       const float* __restrict__ b1, float* __restrict__ h, double* st1) {
    int nt = blockIdx.x & 3;
    int i  = (blockIdx.x >> 2) & 255;
    int b  = blockIdx.x >> 10;
    int n0 = nt * 1024;
    int t  = threadIdx.x;

    const float* xb = x + b * CC * NN;
    const float* wr = w1 + i * CC;

    float a0 = 0.f, a1 = 0.f, a2 = 0.f, a3 = 0.f;
    for (int c = 0; c < CC; c++) {
        float wv = wr[c];
        const float* xr = xb + c * NN + n0 + t;
        a0 = fmaf(wv, xr[0],   a0);
        a1 = fmaf(wv, xr[256], a1);
        a2 = fmaf(wv, xr[512], a2);
        a3 = fmaf(wv, xr[768], a3);
    }
    float bv = b1[i];
    a0 += bv; a1 += bv; a2 += bv; a3 += bv;
    float* hr = h + (b * MM + i) * NN + n0 + t;
    hr[0] = a0; hr[256] = a1; hr[512] = a2; hr[768] = a3;

    float s1 = a0 + a1 + a2 + a3;
    float s2 = a0*a0 + a1*a1 + a2*a2 + a3*a3;
    for (int off = 32; off; off >>= 1) {
        s1 += __shfl_down(s1, off, 64);
        s2 += __shfl_down(s2, off, 64);
    }
    __shared__ float r1[4], r2[4];
    int w = t >> 6, l = t & 63;
    if (l == 0) { r1[w] = s1; r2[w] = s2; }
    __syncthreads();
    if (t == 0) {
        float ts1 = r1[0] + r1[1] + r1[2] + r1[3];
        float ts2 = r2[0] + r2[1] + r2[2] + r2[3];
        int g = i >> 6;
        atomicAdd(&st1[(b * GG + g) * 2 + 0], (double)ts1);
        atomicAdd(&st1[(b * GG + g) * 2 + 1], (double)ts2);
    }
}

// ---------------- gn1 + gelu + wd, transpose to p[b][n][m] ----------------
// grid (N/64, M/64, B), block 256
__global__ void k_gn1t(const float* __restrict__ h, const float* __restrict__ g1,
                       const float* __restrict__ be1, const float* __restrict__ wd,
                       const double* __restrict__ st1, float* __restrict__ p) {
    int n0 = blockIdx.x * 64;
    int m0 = blockIdx.y * 64;
    int b  = blockIdx.z;
    int g  = m0 >> 6;
    double s1 = st1[(b * GG + g) * 2 + 0];
    double s2 = st1[(b * GG + g) * 2 + 1];
    const double cnt = 64.0 * 4096.0;
    double mean_d = s1 / cnt;
    double var_d  = s2 / cnt - mean_d * mean_d;
    float mean = (float)mean_d;
    float rstd = rsqrtf((float)var_d + EPSF);

    __shared__ float tile[64][65];
    int t = threadIdx.x;
    int col = t & 63, row4 = t >> 6;
    #pragma unroll
    for (int i = 0; i < 16; i++) {
        int row = row4 + i * 4;
        int m = m0 + row;
        float hv = h[((b * MM) + m) * NN + n0 + col];
        float a = rstd * g1[m];
        float cc2 = be1[m] - mean * a;
        float u = fmaf(hv, a, cc2);
        tile[row][col] = gelu_exact(u) * wd[m];
    }
    __syncthreads();
    #pragma unroll
    for (int i = 0; i < 16; i++) {
        int ny = row4 + i * 4;
        p[((size_t)(b * NN) + (n0 + ny)) * MM + m0 + col] = tile[col][ny];
    }
}

// ---------------- ball query: one wave per query point ----------------
// grid 2048, block 256 (4 waves)
__global__ void k_ballq(const float* __restrict__ pos, int* __restrict__ idx) {
    int wid  = blockIdx.x * 4 + (threadIdx.x >> 6);
    int lane = threadIdx.x & 63;
    int b = wid >> 12;
    int n = wid & 4095;
    const float* px = pos + b * 3 * NN;
    const float* py = px + NN;
    const float* pz = py + NN;
    float qx = px[n], qy = py[n], qz = pz[n];
    float qsq = qx*qx + qy*qy + qz*qz;
    int* row = idx + (b * NN + n) * KK;

    int found = 0;
    int first = -1;
    const float R2 = 0.04f;
    for (int m0 = 0; m0 < NN && found < KK; m0 += 64) {
        int m = m0 + lane;
        float ax = px[m], ay = py[m], az = pz[m];
        float msq = ax*ax + ay*ay + az*az;
        float dot = qx*ax + qy*ay + qz*az;
        float d = qsq + msq - 2.0f * dot;
        bool hit = !(d > R2);
        unsigned long long mask = __ballot(hit);
        if (first < 0 && mask) first = m0 + (__ffsll((long long)mask) - 1);
        unsigned long long lt = (lane == 0) ? 0ULL : (mask & ((1ULL << lane) - 1ULL));
        int posh = __popcll(lt);
        if (hit && (found + posh) < KK) row[found + posh] = m;
        found += __popcll(mask);
        if (found > KK) found = KK;
    }
    if (lane < KK && lane >= found) row[lane] = first;
}

// ---------------- gather: sign-fused max/min over 32 neighbors + stats2 ----------------
// grid B*N/4 = 2048 blocks, 256 threads; wave w handles point gn = blockIdx.x*4 + w
__global__ void k_gather(const float4* __restrict__ p4, const int* __restrict__ idx,
                         const float* __restrict__ gd, float4* __restrict__ psel,
                         double* st2) {
    int t = threadIdx.x;
    int w = t >> 6, l = t & 63;
    int gn = blockIdx.x * 4 + w;     // 0 .. B*N-1 (blocks never straddle b: N/4 divides evenly)
    int b  = gn >> 12;

    __shared__ float a1[GG], a2[GG];
    if (t < GG) { a1[t] = 0.f; a2[t] = 0.f; }
    __syncthreads();

    int myidx = idx[gn * KK + (l & 31)];
    const float4* pb = p4 + (size_t)b * NN * 64;

    float4 vmax = make_float4(-INFINITY, -INFINITY, -INFINITY, -INFINITY);
    float4 vmin = make_float4( INFINITY,  INFINITY,  INFINITY,  INFINITY);
    float s1 = 0.f, s2 = 0.f;
    #pragma unroll
    for (int k = 0; k < KK; k++) {
        int j = __shfl(myidx, k, 64);
        float4 v = pb[(size_t)j * 64 + l];
        vmax.x = fmaxf(vmax.x, v.x); vmin.x = fminf(vmin.x, v.x);
        vmax.y = fmaxf(vmax.y, v.y); vmin.y = fminf(vmin.y, v.y);
        vmax.z = fmaxf(vmax.z, v.z); vmin.z = fminf(vmin.z, v.z);
        vmax.w = fmaxf(vmax.w, v.w); vmin.w = fminf(vmin.w, v.w);
        s1 += v.x + v.y + v.z + v.w;
        s2 = fmaf(v.x, v.x, s2); s2 = fmaf(v.y, v.y, s2);
        s2 = fmaf(v.z, v.z, s2); s2 = fmaf(v.w, v.w, s2);
    }

    float4 gd4 = ((const float4*)gd)[l];
    float4 sel;
    sel.x = (gd4.x >= 0.f) ? vmax.x : vmin.x;
    sel.y = (gd4.y >= 0.f) ? vmax.y : vmin.y;
    sel.z = (gd4.z >= 0.f) ? vmax.z : vmin.z;
    sel.w = (gd4.w >= 0.f) ? vmax.w : vmin.w;
    psel[(size_t)gn * 64 + l] = sel;

    // stats per 16-lane segment (lane l covers channels 4l..4l+3; group = l>>4)
    for (int off = 8; off; off >>= 1) {
        s1 += __shfl_down(s1, off, 64);
        s2 += __shfl_down(s2, off, 64);
    }
    if ((l & 15) == 0) {
        int g = l >> 4;
        atomicAdd(&a1[g], s1);
        atomicAdd(&a2[g], s2);
    }
    __syncthreads();
    if (t < GG) {
        atomicAdd(&st2[(b * GG + t) * 2 + 0], (double)a1[t]);
        atomicAdd(&st2[(b * GG + t) * 2 + 1], (double)a2[t]);
    }
}

// ---------------- mlp2: h2 = gelu(gn2(sel)), o = w2 @ h2 + b2, stats3 ----------------
// grid B*N/4 = 2048 blocks, block 256, 4 points per block
__global__ void k_mlp2(const float* __restrict__ psel,
                       const float* __restrict__ w2, const float* __restrict__ b2,
                       const float* __restrict__ gd, const float* __restrict__ bed,
                       const double* __restrict__ st2, float* __restrict__ oraw, double* st3) {
    int b  = blockIdx.x >> 10;
    int n0 = (blockIdx.x & 1023) * 4;
    int t  = threadIdx.x;

    int g = t >> 6;
    const double cnt2 = 64.0 * 4096.0 * 32.0;
    double mean_d = st2[(b * GG + g) * 2 + 0] / cnt2;
    double var_d  = st2[(b * GG + g) * 2 + 1] / cnt2 - mean_d * mean_d;
    float rstd = rsqrtf((float)var_d + EPSF);
    float a = rstd * gd[t];
    float cadd = bed[t] - (float)mean_d * a;

    int cc = t >> 2, q = t & 3;
    float w[64];
    #pragma unroll
    for (int j = 0; j < 64; j++) w[j] = w2[cc * MM + q * 64 + j];

    __shared__ float sh2[256];
    __shared__ float sred[64][5];
    float so1 = 0.f, so2 = 0.f;

    for (int nn = 0; nn < 4; nn++) {
        int n = n0 + nn;
        float vm = psel[((size_t)(b * NN) + n) * MM + t];
        float u = fmaf(vm, a, cadd);
        float h2 = gelu_exact(u);
        __syncthreads();
        sh2[t] = h2;
        __syncthreads();
        float acc = 0.f;
        #pragma unroll
        for (int j = 0; j < 64; j++) acc = fmaf(w[j], sh2[q * 64 + j], acc);
        sred[cc][q] = acc;
        __syncthreads();
        if (t < 64) {
            float o = b2[t] + sred[t][0] + sred[t][1] + sred[t][2] + sred[t][3];
            oraw[((size_t)(b * CC) + t) * NN + n] = o;
            so1 += o;
            so2 = fmaf(o, o, so2);
        }
    }
    if (t < 64) {
        for (int off = 8; off; off >>= 1) {
            so1 += __shfl_down(so1, off, 64);
            so2 += __shfl_down(so2, off, 64);
        }
        if ((t & 15) == 0) {
            int g3 = t >> 4;
            atomicAdd(&st3[(b * GG + g3) * 2 + 0], (double)so1);
            atomicAdd(&st3[(b * GG + g3) * 2 + 1], (double)so2);
        }
    }
}

// ---------------- final: gn3 + residual ----------------
// grid 2048, block 256
__global__ void k_final(const float* __restrict__ oraw, const float* __restrict__ x,
                        const float* __restrict__ g2, const float* __restrict__ be2,
                        const double* __restrict__ st3, float* __restrict__ out) {
    int gid = blockIdx.x * 256 + threadIdx.x;
    int c = (gid >> 12) & 63;
    int b = gid >> 18;
    int g = c >> 4;
    const double cnt = 16.0 * 4096.0;
    double mean_d = st3[(b * GG + g) * 2 + 0] / cnt;
    double var_d  = st3[(b * GG + g) * 2 + 1] / cnt - mean_d * mean_d;
    float rstd = rsqrtf((float)var_d + EPSF);
    float o = oraw[gid];
    out[gid] = (o - (float)mean_d) * rstd * g2[c] + be2[c] + x[gid];
}

// ---------------- launch ----------------
extern "C" void kernel_launch(void* const* d_in, const int* in_sizes, int n_in,
                              void* d_out, int out_size, void* d_ws, size_t ws_size,
                              hipStream_t stream) {
    const float* x   = (const float*)d_in[0];
    const float* pos = (const float*)d_in[1];
    const float* w1  = (const float*)d_in[2];
    const float* b1  = (const float*)d_in[3];
    const float* g1  = (const float*)d_in[4];
    const float* be1 = (const float*)d_in[5];
    const float* wd  = (const float*)d_in[6];
    const float* gd  = (const float*)d_in[7];
    const float* bed = (const float*)d_in[8];
    const float* w2  = (const float*)d_in[9];
    const float* b2  = (const float*)d_in[10];
    const float* g2  = (const float*)d_in[11];
    const float* be2 = (const float*)d_in[12];
    float* out = (float*)d_out;

    float* ws = (float*)d_ws;
    const size_t SZ = (size_t)BB * MM * NN;          // 2,097,152 floats
    float* h    = ws;                                // 8 MB
    float* p    = ws + SZ;                           // 8 MB
    float* psel = ws + 2 * SZ;                       // 8 MB
    float* oraw = ws + 3 * SZ;                       // 2 MB (B*C*N)
    char* after = (char*)(oraw + (size_t)BB * CC * NN);
    int* idx = (int*)after;                          // 1 MB
    double* st = (double*)(after + (size_t)BB * NN * KK * sizeof(int));
    double* st1 = st;
    double* st2 = st + 16;
    double* st3 = st + 32;

    k_init<<<1, 64, 0, stream>>>(st);
    k_mlp1<<<2048, 256, 0, stream>>>(x, w1, b1, h, st1);
    k_gn1t<<<dim3(64, 4, 2), 256, 0, stream>>>(h, g1, be1, wd, st1, p);
    k_ballq<<<2048, 256, 0, stream>>>(pos, idx);
    k_gather<<<2048, 256, 0, stream>>>((const float4*)p, idx, gd, (float4*)psel, st2);
    k_mlp2<<<2048, 256, 0, stream>>>(psel, w2, b2, gd, bed, st2, oraw, st3);
    k_final<<<2048, 256, 0, stream>>>(oraw, x, g2, be2, st3, out);
}

// Round 3
// 254.745 us; speedup vs baseline: 1.0311x; 1.0255x over previous
//
#include <hip/hip_runtime.h>
#include <math.h>

#define BB 2
#define CC 64
#define NN 4096
#define MM 256
#define KK 32
#define GG 4
#define EPSF 1e-5f

__device__ __forceinline__ float gelu_exact(float x) {
    return 0.5f * x * (1.0f + erff(x * 0.70710678118654752f));
}

// ---------------- init: zero the 48 stat doubles ----------------
__global__ void k_init(double* st) {
    int t = threadIdx.x;
    if (t < 48) st[t] = 0.0;
}

// ---------------- mlp1: h = w1 @ x + b1, accumulate stats1 ----------------
// grid 512 = B(2) x MT(8 tiles of 32 m) x NT(32 tiles of 128 n), block 256
__global__ void k_mlp1(const float* __restrict__ x, const float* __restrict__ w1,
                       const float* __restrict__ b1, float* __restrict__ h, double* st1) {
    __shared__ float xs[64 * 128];     // 32 KB: x tile [c][n]
    __shared__ float w1t[64 * 32];     // 8 KB: w1 transposed [c][m_local]
    __shared__ float r1[4], r2[4];

    int bx = blockIdx.x;
    int nt = bx & 31, mt = (bx >> 5) & 7, b = bx >> 8;
    int n0 = nt * 128, m0 = mt * 32;
    int t = threadIdx.x;

    // stage x tile (64 c x 128 n), coalesced float4
    {
        int nq = t & 31, ch = t >> 5;
        #pragma unroll
        for (int p = 0; p < 8; p++) {
            int c = p * 8 + ch;
            float4 v = *(const float4*)&x[((size_t)(b * CC + c)) * NN + n0 + nq * 4];
            *(float4*)&xs[c * 128 + nq * 4] = v;
        }
    }
    // stage w1 tile transposed
    {
        #pragma unroll
        for (int p = 0; p < 2; p++) {
            int idx = p * 256 + t;           // 0..511
            int m = idx >> 4, cq = idx & 15;
            float4 v = *(const float4*)&w1[(m0 + m) * CC + cq * 4];
            w1t[(cq * 4 + 0) * 32 + m] = v.x;
            w1t[(cq * 4 + 1) * 32 + m] = v.y;
            w1t[(cq * 4 + 2) * 32 + m] = v.z;
            w1t[(cq * 4 + 3) * 32 + m] = v.w;
        }
    }
    __syncthreads();

    int nq = t & 31;          // handles n = n0 + nq*4 .. +3
    int mseg = t >> 5;        // handles m = m0 + mseg*4 .. +3
    float o[4][4];
    #pragma unroll
    for (int i = 0; i < 4; i++)
        #pragma unroll
        for (int j = 0; j < 4; j++) o[i][j] = 0.f;

    for (int c = 0; c < 64; c++) {
        float4 xv = *(float4*)&xs[c * 128 + nq * 4];
        float4 wv = *(float4*)&w1t[c * 32 + mseg * 4];
        o[0][0] = fmaf(wv.x, xv.x, o[0][0]); o[0][1] = fmaf(wv.x, xv.y, o[0][1]);
        o[0][2] = fmaf(wv.x, xv.z, o[0][2]); o[0][3] = fmaf(wv.x, xv.w, o[0][3]);
        o[1][0] = fmaf(wv.y, xv.x, o[1][0]); o[1][1] = fmaf(wv.y, xv.y, o[1][1]);
        o[1][2] = fmaf(wv.y, xv.z, o[1][2]); o[1][3] = fmaf(wv.y, xv.w, o[1][3]);
        o[2][0] = fmaf(wv.z, xv.x, o[2][0]); o[2][1] = fmaf(wv.z, xv.y, o[2][1]);
        o[2][2] = fmaf(wv.z, xv.z, o[2][2]); o[2][3] = fmaf(wv.z, xv.w, o[2][3]);
        o[3][0] = fmaf(wv.w, xv.x, o[3][0]); o[3][1] = fmaf(wv.w, xv.y, o[3][1]);
        o[3][2] = fmaf(wv.w, xv.z, o[3][2]); o[3][3] = fmaf(wv.w, xv.w, o[3][3]);
    }

    float s1 = 0.f, s2 = 0.f;
    #pragma unroll
    for (int mi = 0; mi < 4; mi++) {
        int m = m0 + mseg * 4 + mi;
        float bv = b1[m];
        float4 r;
        r.x = o[mi][0] + bv; r.y = o[mi][1] + bv;
        r.z = o[mi][2] + bv; r.w = o[mi][3] + bv;
        *(float4*)&h[((size_t)(b * MM + m)) * NN + n0 + nq * 4] = r;
        s1 += r.x + r.y + r.z + r.w;
        s2 = fmaf(r.x, r.x, s2); s2 = fmaf(r.y, r.y, s2);
        s2 = fmaf(r.z, r.z, s2); s2 = fmaf(r.w, r.w, s2);
    }
    for (int off = 32; off; off >>= 1) {
        s1 += __shfl_down(s1, off, 64);
        s2 += __shfl_down(s2, off, 64);
    }
    int w = t >> 6, l = t & 63;
    if (l == 0) { r1[w] = s1; r2[w] = s2; }
    __syncthreads();
    if (t == 0) {
        float ts1 = r1[0] + r1[1] + r1[2] + r1[3];
        float ts2 = r2[0] + r2[1] + r2[2] + r2[3];
        int g = m0 >> 6;
        atomicAdd(&st1[(b * GG + g) * 2 + 0], (double)ts1);
        atomicAdd(&st1[(b * GG + g) * 2 + 1], (double)ts2);
    }
}

// ---------------- gn1 + gelu + wd, transpose to p[b][n][m] ----------------
// grid (N/64, M/64, B), block 256
__global__ void k_gn1t(const float* __restrict__ h, const float* __restrict__ g1,
                       const float* __restrict__ be1, const float* __restrict__ wd,
                       const double* __restrict__ st1, float* __restrict__ p) {
    int n0 = blockIdx.x * 64;
    int m0 = blockIdx.y * 64;
    int b  = blockIdx.z;
    int g  = m0 >> 6;
    double s1 = st1[(b * GG + g) * 2 + 0];
    double s2 = st1[(b * GG + g) * 2 + 1];
    const double cnt = 64.0 * 4096.0;
    double mean_d = s1 / cnt;
    double var_d  = s2 / cnt - mean_d * mean_d;
    float mean = (float)mean_d;
    float rstd = rsqrtf((float)var_d + EPSF);

    __shared__ float tile[64 * 65];
    int t = threadIdx.x;
    int nq = t & 15, mr = t >> 4;
    #pragma unroll
    for (int pp = 0; pp < 4; pp++) {
        int row = pp * 16 + mr;
        int m = m0 + row;
        float a = rstd * g1[m];
        float cc2 = be1[m] - mean * a;
        float wdm = wd[m];
        float4 hv = *(const float4*)&h[((size_t)(b * MM + m)) * NN + n0 + nq * 4];
        tile[row * 65 + nq * 4 + 0] = gelu_exact(fmaf(hv.x, a, cc2)) * wdm;
        tile[row * 65 + nq * 4 + 1] = gelu_exact(fmaf(hv.y, a, cc2)) * wdm;
        tile[row * 65 + nq * 4 + 2] = gelu_exact(fmaf(hv.z, a, cc2)) * wdm;
        tile[row * 65 + nq * 4 + 3] = gelu_exact(fmaf(hv.w, a, cc2)) * wdm;
    }
    __syncthreads();
    #pragma unroll
    for (int pp = 0; pp < 4; pp++) {
        int idx = pp * 256 + t;
        int nl = idx >> 4, mq = idx & 15;
        float4 v;
        v.x = tile[(mq * 4 + 0) * 65 + nl];
        v.y = tile[(mq * 4 + 1) * 65 + nl];
        v.z = tile[(mq * 4 + 2) * 65 + nl];
        v.w = tile[(mq * 4 + 3) * 65 + nl];
        *(float4*)&p[((size_t)(b * NN) + n0 + nl) * MM + m0 + mq * 4] = v;
    }
}

// ---------------- ball query: one wave per query point ----------------
// grid 2048, block 256 (4 waves)
__global__ void k_ballq(const float* __restrict__ pos, int* __restrict__ idx) {
    int wid  = blockIdx.x * 4 + (threadIdx.x >> 6);
    int lane = threadIdx.x & 63;
    int b = wid >> 12;
    int n = wid & 4095;
    const float* px = pos + b * 3 * NN;
    const float* py = px + NN;
    const float* pz = py + NN;
    float qx = px[n], qy = py[n], qz = pz[n];
    float qsq = qx*qx + qy*qy + qz*qz;
    int* row = idx + (b * NN + n) * KK;

    int found = 0;
    int first = -1;
    const float R2 = 0.04f;
    for (int m0 = 0; m0 < NN && found < KK; m0 += 64) {
        int m = m0 + lane;
        float ax = px[m], ay = py[m], az = pz[m];
        float msq = ax*ax + ay*ay + az*az;
        float dot = qx*ax + qy*ay + qz*az;
        float d = qsq + msq - 2.0f * dot;
        bool hit = !(d > R2);
        unsigned long long mask = __ballot(hit);
        if (first < 0 && mask) first = m0 + (__ffsll((long long)mask) - 1);
        unsigned long long lt = (lane == 0) ? 0ULL : (mask & ((1ULL << lane) - 1ULL));
        int posh = __popcll(lt);
        if (hit && (found + posh) < KK) row[found + posh] = m;
        found += __popcll(mask);
        if (found > KK) found = KK;
    }
    if (lane < KK && lane >= found) row[lane] = first;
}

// ---------------- gather: sign-fused max/min over 32 neighbors + stats2 ----------------
// grid B*N/4 = 2048 blocks, 256 threads; wave w handles point gn = blockIdx.x*4 + w
__global__ void k_gather(const float4* __restrict__ p4, const int* __restrict__ idx,
                         const float* __restrict__ gd, float4* __restrict__ psel,
                         double* st2) {
    int t = threadIdx.x;
    int w = t >> 6, l = t & 63;
    int gn = blockIdx.x * 4 + w;
    int b  = gn >> 12;

    __shared__ float a1[GG], a2[GG];
    if (t < GG) { a1[t] = 0.f; a2[t] = 0.f; }
    __syncthreads();

    int myidx = idx[gn * KK + (l & 31)];
    const float4* pb = p4 + (size_t)b * NN * 64;

    float4 vmax = make_float4(-INFINITY, -INFINITY, -INFINITY, -INFINITY);
    float4 vmin = make_float4( INFINITY,  INFINITY,  INFINITY,  INFINITY);
    float s1 = 0.f, s2 = 0.f;
    #pragma unroll
    for (int k = 0; k < KK; k++) {
        int j = __shfl(myidx, k, 64);
        float4 v = pb[(size_t)j * 64 + l];
        vmax.x = fmaxf(vmax.x, v.x); vmin.x = fminf(vmin.x, v.x);
        vmax.y = fmaxf(vmax.y, v.y); vmin.y = fminf(vmin.y, v.y);
        vmax.z = fmaxf(vmax.z, v.z); vmin.z = fminf(vmin.z, v.z);
        vmax.w = fmaxf(vmax.w, v.w); vmin.w = fminf(vmin.w, v.w);
        s1 += v.x + v.y + v.z + v.w;
        s2 = fmaf(v.x, v.x, s2); s2 = fmaf(v.y, v.y, s2);
        s2 = fmaf(v.z, v.z, s2); s2 = fmaf(v.w, v.w, s2);
    }

    float4 gd4 = ((const float4*)gd)[l];
    float4 sel;
    sel.x = (gd4.x >= 0.f) ? vmax.x : vmin.x;
    sel.y = (gd4.y >= 0.f) ? vmax.y : vmin.y;
    sel.z = (gd4.z >= 0.f) ? vmax.z : vmin.z;
    sel.w = (gd4.w >= 0.f) ? vmax.w : vmin.w;
    psel[(size_t)gn * 64 + l] = sel;

    for (int off = 8; off; off >>= 1) {
        s1 += __shfl_down(s1, off, 64);
        s2 += __shfl_down(s2, off, 64);
    }
    if ((l & 15) == 0) {
        int g = l >> 4;
        atomicAdd(&a1[g], s1);
        atomicAdd(&a2[g], s2);
    }
    __syncthreads();
    if (t < GG) {
        atomicAdd(&st2[(b * GG + t) * 2 + 0], (double)a1[t]);
        atomicAdd(&st2[(b * GG + t) * 2 + 1], (double)a2[t]);
    }
}

// ---------------- mlp2: h2 = gelu(gn2(sel)), o = w2 @ h2 + b2, stats3 ----------------
// grid 1024 blocks, block 256; block handles 8 points; wave w owns c-range [16w,16w+16)
__global__ void k_mlp2(const float* __restrict__ psel,
                       const float* __restrict__ w2, const float* __restrict__ b2,
                       const float* __restrict__ gd, const float* __restrict__ bed,
                       const double* __restrict__ st2, float* __restrict__ oraw, double* st3) {
    __shared__ float h2s[8 * 272];     // per point: 4 quarters stride 68 (bank-disjoint)
    int gnb = blockIdx.x * 8;
    int b = gnb >> 12;
    int n0 = gnb & 4095;
    int t = threadIdx.x;

    const double cnt2 = 64.0 * 4096.0 * 32.0;
    float meanf[4], rstdf[4];
    #pragma unroll
    for (int g = 0; g < 4; g++) {
        double m_ = st2[(b * GG + g) * 2 + 0] / cnt2;
        double v_ = st2[(b * GG + g) * 2 + 1] / cnt2 - m_ * m_;
        meanf[g] = (float)m_;
        rstdf[g] = rsqrtf((float)v_ + EPSF);
    }

    #pragma unroll
    for (int pp = 0; pp < 2; pp++) {
        int fidx = pp * 1024 + t * 4;
        int j = fidx >> 8, m = fidx & 255;
        int g = m >> 6;
        float4 v   = *(const float4*)&psel[((size_t)(gnb + j)) * MM + m];
        float4 gdv = *(const float4*)&gd[m];
        float4 bev = *(const float4*)&bed[m];
        float a0 = rstdf[g] * gdv.x, a1_ = rstdf[g] * gdv.y;
        float a2_ = rstdf[g] * gdv.z, a3_ = rstdf[g] * gdv.w;
        float4 r;
        r.x = gelu_exact(fmaf(v.x, a0,  bev.x - meanf[g] * a0));
        r.y = gelu_exact(fmaf(v.y, a1_, bev.y - meanf[g] * a1_));
        r.z = gelu_exact(fmaf(v.z, a2_, bev.z - meanf[g] * a2_));
        r.w = gelu_exact(fmaf(v.w, a3_, bev.w - meanf[g] * a3_));
        *(float4*)&h2s[j * 272 + g * 68 + (m & 63)] = r;
    }
    __syncthreads();

    int l = t & 63, w = t >> 6;
    int ci = l & 15, q = l >> 4;
    int c = w * 16 + ci;

    float4 wreg[16];
    #pragma unroll
    for (int k = 0; k < 16; k++)
        wreg[k] = *(const float4*)&w2[c * MM + q * 64 + k * 4];

    float acc[8];
    #pragma unroll
    for (int j = 0; j < 8; j++) acc[j] = 0.f;

    #pragma unroll
    for (int k = 0; k < 16; k++) {
        float4 wv = wreg[k];
        #pragma unroll
        for (int j = 0; j < 8; j++) {
            float4 hv = *(float4*)&h2s[j * 272 + q * 68 + k * 4];
            acc[j] = fmaf(wv.x, hv.x, acc[j]);
            acc[j] = fmaf(wv.y, hv.y, acc[j]);
            acc[j] = fmaf(wv.z, hv.z, acc[j]);
            acc[j] = fmaf(wv.w, hv.w, acc[j]);
        }
    }

    float bias = b2[c];
    float ov[8];
    float so1 = 0.f, so2 = 0.f;
    #pragma unroll
    for (int j = 0; j < 8; j++) {
        float v = acc[j];
        v += __shfl_xor(v, 16, 64);
        v += __shfl_xor(v, 32, 64);
        ov[j] = v + bias;
        so1 += ov[j];
        so2 = fmaf(ov[j], ov[j], so2);
    }
    if (l < 16) {
        float* dst = &oraw[((size_t)(b * CC) + c) * NN + n0];
        *(float4*)&dst[0] = make_float4(ov[0], ov[1], ov[2], ov[3]);
        *(float4*)&dst[4] = make_float4(ov[4], ov[5], ov[6], ov[7]);
    } else {
        so1 = 0.f; so2 = 0.f;
    }
    so1 += __shfl_down(so1, 8, 16); so2 += __shfl_down(so2, 8, 16);
    so1 += __shfl_down(so1, 4, 16); so2 += __shfl_down(so2, 4, 16);
    so1 += __shfl_down(so1, 2, 16); so2 += __shfl_down(so2, 2, 16);
    so1 += __shfl_down(so1, 1, 16); so2 += __shfl_down(so2, 1, 16);
    if (l == 0) {
        atomicAdd(&st3[(b * GG + w) * 2 + 0], (double)so1);
        atomicAdd(&st3[(b * GG + w) * 2 + 1], (double)so2);
    }
}

// ---------------- final: gn3 + residual (float4) ----------------
// grid 512, block 256
__global__ void k_final(const float* __restrict__ oraw, const float* __restrict__ x,
                        const float* __restrict__ g2, const float* __restrict__ be2,
                        const double* __restrict__ st3, float* __restrict__ out) {
    int i4 = blockIdx.x * 256 + threadIdx.x;
    int base = i4 * 4;
    int c = (base >> 12) & 63;
    int b = base >> 18;
    int g = c >> 4;
    const double cnt = 16.0 * 4096.0;
    double mean_d = st3[(b * GG + g) * 2 + 0] / cnt;
    double var_d  = st3[(b * GG + g) * 2 + 1] / cnt - mean_d * mean_d;
    float mean = (float)mean_d;
    float rstd = rsqrtf((float)var_d + EPSF);
    float sc = rstd * g2[c];
    float ad = be2[c] - mean * sc;
    float4 o = ((const float4*)oraw)[i4];
    float4 xv = ((const float4*)x)[i4];
    float4 r;
    r.x = fmaf(o.x, sc, ad) + xv.x;
    r.y = fmaf(o.y, sc, ad) + xv.y;
    r.z = fmaf(o.z, sc, ad) + xv.z;
    r.w = fmaf(o.w, sc, ad) + xv.w;
    ((float4*)out)[i4] = r;
}

// ---------------- launch ----------------
extern "C" void kernel_launch(void* const* d_in, const int* in_sizes, int n_in,
                              void* d_out, int out_size, void* d_ws, size_t ws_size,
                              hipStream_t stream) {
    const float* x   = (const float*)d_in[0];
    const float* pos = (const float*)d_in[1];
    const float* w1  = (const float*)d_in[2];
    const float* b1  = (const float*)d_in[3];
    const float* g1  = (const float*)d_in[4];
    const float* be1 = (const float*)d_in[5];
    const float* wd  = (const float*)d_in[6];
    const float* gd  = (const float*)d_in[7];
    const float* bed = (const float*)d_in[8];
    const float* w2  = (const float*)d_in[9];
    const float* b2  = (const float*)d_in[10];
    const float* g2  = (const float*)d_in[11];
    const float* be2 = (const float*)d_in[12];
    float* out = (float*)d_out;

    float* ws = (float*)d_ws;
    const size_t SZ = (size_t)BB * MM * NN;
    float* h    = ws;
    float* p    = ws + SZ;
    float* psel = ws + 2 * SZ;
    float* oraw = ws + 3 * SZ;
    char* after = (char*)(oraw + (size_t)BB * CC * NN);
    int* idx = (int*)after;
    double* st = (double*)(after + (size_t)BB * NN * KK * sizeof(int));
    double* st1 = st;
    double* st2 = st + 16;
    double* st3 = st + 32;

    k_init<<<1, 64, 0, stream>>>(st);
    k_mlp1<<<512, 256, 0, stream>>>(x, w1, b1, h, st1);
    k_gn1t<<<dim3(64, 4, 2), 256, 0, stream>>>(h, g1, be1, wd, st1, p);
    k_ballq<<<2048, 256, 0, stream>>>(pos, idx);
    k_gather<<<2048, 256, 0, stream>>>((const float4*)p, idx, gd, (float4*)psel, st2);
    k_mlp2<<<1024, 256, 0, stream>>>(psel, w2, b2, gd, bed, st2, oraw, st3);
    k_final<<<512, 256, 0, stream>>>(oraw, x, g2, be2, st3, out);
}

// Round 4
// 203.622 us; speedup vs baseline: 1.2899x; 1.2511x over previous
//
#include <hip/hip_runtime.h>
#include <math.h>

#define BB 2
#define CC 64
#define NN 4096
#define MM 256
#define KK 32
#define GG 4
#define EPSF 1e-5f

__device__ __forceinline__ float gelu_exact(float x) {
    return 0.5f * x * (1.0f + erff(x * 0.70710678118654752f));
}

__device__ __forceinline__ float bcast_lane(float v, int lane) {
    return __int_as_float(__builtin_amdgcn_readlane(__float_as_int(v), lane));
}

// ---------------- init: zero the 48 stat doubles ----------------
__global__ void k_init(double* st) {
    int t = threadIdx.x;
    if (t < 48) st[t] = 0.0;
}

// ---------------- mlp1: h = w1 @ x + b1, accumulate stats1 ----------------
// grid 512 = B(2) x MT(8 tiles of 32 m) x NT(32 tiles of 128 n), block 256
__global__ void k_mlp1(const float* __restrict__ x, const float* __restrict__ w1,
                       const float* __restrict__ b1, float* __restrict__ h, double* st1) {
    __shared__ float xs[64 * 128];     // 32 KB: x tile [c][n]
    __shared__ float w1t[64 * 32];     // 8 KB: w1 transposed [c][m_local]
    __shared__ float r1[4], r2[4];

    int bx = blockIdx.x;
    int nt = bx & 31, mt = (bx >> 5) & 7, b = bx >> 8;
    int n0 = nt * 128, m0 = mt * 32;
    int t = threadIdx.x;

    {
        int nq = t & 31, ch = t >> 5;
        #pragma unroll
        for (int p = 0; p < 8; p++) {
            int c = p * 8 + ch;
            float4 v = *(const float4*)&x[((size_t)(b * CC + c)) * NN + n0 + nq * 4];
            *(float4*)&xs[c * 128 + nq * 4] = v;
        }
    }
    {
        #pragma unroll
        for (int p = 0; p < 2; p++) {
            int idx = p * 256 + t;
            int m = idx >> 4, cq = idx & 15;
            float4 v = *(const float4*)&w1[(m0 + m) * CC + cq * 4];
            w1t[(cq * 4 + 0) * 32 + m] = v.x;
            w1t[(cq * 4 + 1) * 32 + m] = v.y;
            w1t[(cq * 4 + 2) * 32 + m] = v.z;
            w1t[(cq * 4 + 3) * 32 + m] = v.w;
        }
    }
    __syncthreads();

    int nq = t & 31;
    int mseg = t >> 5;
    float o[4][4];
    #pragma unroll
    for (int i = 0; i < 4; i++)
        #pragma unroll
        for (int j = 0; j < 4; j++) o[i][j] = 0.f;

    for (int c = 0; c < 64; c++) {
        float4 xv = *(float4*)&xs[c * 128 + nq * 4];
        float4 wv = *(float4*)&w1t[c * 32 + mseg * 4];
        o[0][0] = fmaf(wv.x, xv.x, o[0][0]); o[0][1] = fmaf(wv.x, xv.y, o[0][1]);
        o[0][2] = fmaf(wv.x, xv.z, o[0][2]); o[0][3] = fmaf(wv.x, xv.w, o[0][3]);
        o[1][0] = fmaf(wv.y, xv.x, o[1][0]); o[1][1] = fmaf(wv.y, xv.y, o[1][1]);
        o[1][2] = fmaf(wv.y, xv.z, o[1][2]); o[1][3] = fmaf(wv.y, xv.w, o[1][3]);
        o[2][0] = fmaf(wv.z, xv.x, o[2][0]); o[2][1] = fmaf(wv.z, xv.y, o[2][1]);
        o[2][2] = fmaf(wv.z, xv.z, o[2][2]); o[2][3] = fmaf(wv.z, xv.w, o[2][3]);
        o[3][0] = fmaf(wv.w, xv.x, o[3][0]); o[3][1] = fmaf(wv.w, xv.y, o[3][1]);
        o[3][2] = fmaf(wv.w, xv.z, o[3][2]); o[3][3] = fmaf(wv.w, xv.w, o[3][3]);
    }

    float s1 = 0.f, s2 = 0.f;
    #pragma unroll
    for (int mi = 0; mi < 4; mi++) {
        int m = m0 + mseg * 4 + mi;
        float bv = b1[m];
        float4 r;
        r.x = o[mi][0] + bv; r.y = o[mi][1] + bv;
        r.z = o[mi][2] + bv; r.w = o[mi][3] + bv;
        *(float4*)&h[((size_t)(b * MM + m)) * NN + n0 + nq * 4] = r;
        s1 += r.x + r.y + r.z + r.w;
        s2 = fmaf(r.x, r.x, s2); s2 = fmaf(r.y, r.y, s2);
        s2 = fmaf(r.z, r.z, s2); s2 = fmaf(r.w, r.w, s2);
    }
    for (int off = 32; off; off >>= 1) {
        s1 += __shfl_down(s1, off, 64);
        s2 += __shfl_down(s2, off, 64);
    }
    int w = t >> 6, l = t & 63;
    if (l == 0) { r1[w] = s1; r2[w] = s2; }
    __syncthreads();
    if (t == 0) {
        float ts1 = r1[0] + r1[1] + r1[2] + r1[3];
        float ts2 = r2[0] + r2[1] + r2[2] + r2[3];
        int g = m0 >> 6;
        atomicAdd(&st1[(b * GG + g) * 2 + 0], (double)ts1);
        atomicAdd(&st1[(b * GG + g) * 2 + 1], (double)ts2);
    }
}

// ---------------- gn1 + gelu + wd, transpose to p[b][n][m] ----------------
// grid (N/64, M/64, B), block 256
__global__ void k_gn1t(const float* __restrict__ h, const float* __restrict__ g1,
                       const float* __restrict__ be1, const float* __restrict__ wd,
                       const double* __restrict__ st1, float* __restrict__ p) {
    int n0 = blockIdx.x * 64;
    int m0 = blockIdx.y * 64;
    int b  = blockIdx.z;
    int g  = m0 >> 6;
    double s1 = st1[(b * GG + g) * 2 + 0];
    double s2 = st1[(b * GG + g) * 2 + 1];
    const double cnt = 64.0 * 4096.0;
    double mean_d = s1 / cnt;
    double var_d  = s2 / cnt - mean_d * mean_d;
    float mean = (float)mean_d;
    float rstd = rsqrtf((float)var_d + EPSF);

    __shared__ float tile[64 * 65];
    int t = threadIdx.x;
    int nq = t & 15, mr = t >> 4;
    #pragma unroll
    for (int pp = 0; pp < 4; pp++) {
        int row = pp * 16 + mr;
        int m = m0 + row;
        float a = rstd * g1[m];
        float cc2 = be1[m] - mean * a;
        float wdm = wd[m];
        float4 hv = *(const float4*)&h[((size_t)(b * MM + m)) * NN + n0 + nq * 4];
        tile[row * 65 + nq * 4 + 0] = gelu_exact(fmaf(hv.x, a, cc2)) * wdm;
        tile[row * 65 + nq * 4 + 1] = gelu_exact(fmaf(hv.y, a, cc2)) * wdm;
        tile[row * 65 + nq * 4 + 2] = gelu_exact(fmaf(hv.z, a, cc2)) * wdm;
        tile[row * 65 + nq * 4 + 3] = gelu_exact(fmaf(hv.w, a, cc2)) * wdm;
    }
    __syncthreads();
    #pragma unroll
    for (int pp = 0; pp < 4; pp++) {
        int idx = pp * 256 + t;
        int nl = idx >> 4, mq = idx & 15;
        float4 v;
        v.x = tile[(mq * 4 + 0) * 65 + nl];
        v.y = tile[(mq * 4 + 1) * 65 + nl];
        v.z = tile[(mq * 4 + 2) * 65 + nl];
        v.w = tile[(mq * 4 + 3) * 65 + nl];
        *(float4*)&p[((size_t)(b * NN) + n0 + nl) * MM + m0 + mq * 4] = v;
    }
}

// ---------------- ball query: one wave per query point ----------------
// grid 2048, block 256 (4 waves)
__global__ void k_ballq(const float* __restrict__ pos, int* __restrict__ idx) {
    int wid  = blockIdx.x * 4 + (threadIdx.x >> 6);
    int lane = threadIdx.x & 63;
    int b = wid >> 12;
    int n = wid & 4095;
    const float* px = pos + b * 3 * NN;
    const float* py = px + NN;
    const float* pz = py + NN;
    float qx = px[n], qy = py[n], qz = pz[n];
    float qsq = qx*qx + qy*qy + qz*qz;
    int* row = idx + (b * NN + n) * KK;

    int found = 0;
    int first = -1;
    const float R2 = 0.04f;
    for (int m0 = 0; m0 < NN && found < KK; m0 += 64) {
        int m = m0 + lane;
        float ax = px[m], ay = py[m], az = pz[m];
        float msq = ax*ax + ay*ay + az*az;
        float dot = qx*ax + qy*ay + qz*az;
        float d = qsq + msq - 2.0f * dot;
        bool hit = !(d > R2);
        unsigned long long mask = __ballot(hit);
        if (first < 0 && mask) first = m0 + (__ffsll((long long)mask) - 1);
        unsigned long long lt = (lane == 0) ? 0ULL : (mask & ((1ULL << lane) - 1ULL));
        int posh = __popcll(lt);
        if (hit && (found + posh) < KK) row[found + posh] = m;
        found += __popcll(mask);
        if (found > KK) found = KK;
    }
    if (lane < KK && lane >= found) row[lane] = first;
}

// ---------------- gather: sign-fused max/min over 32 neighbors + stats2 ----------------
// grid B*N/4 = 2048 blocks, 256 threads; wave w handles point gn = blockIdx.x*4 + w
__global__ void k_gather(const float4* __restrict__ p4, const int* __restrict__ idx,
                         const float* __restrict__ gd, float4* __restrict__ psel,
                         double* st2) {
    int t = threadIdx.x;
    int w = t >> 6, l = t & 63;
    int gn = blockIdx.x * 4 + w;
    int b  = gn >> 12;

    __shared__ float a1[GG], a2[GG];
    if (t < GG) { a1[t] = 0.f; a2[t] = 0.f; }
    __syncthreads();

    int myidx = idx[gn * KK + (l & 31)];
    const float4* pb = p4 + (size_t)b * NN * 64;

    float4 vmax = make_float4(-INFINITY, -INFINITY, -INFINITY, -INFINITY);
    float4 vmin = make_float4( INFINITY,  INFINITY,  INFINITY,  INFINITY);
    float s1 = 0.f, s2 = 0.f;
    #pragma unroll
    for (int k = 0; k < KK; k++) {
        int j = __shfl(myidx, k, 64);
        float4 v = pb[(size_t)j * 64 + l];
        vmax.x = fmaxf(vmax.x, v.x); vmin.x = fminf(vmin.x, v.x);
        vmax.y = fmaxf(vmax.y, v.y); vmin.y = fminf(vmin.y, v.y);
        vmax.z = fmaxf(vmax.z, v.z); vmin.z = fminf(vmin.z, v.z);
        vmax.w = fmaxf(vmax.w, v.w); vmin.w = fminf(vmin.w, v.w);
        s1 += v.x + v.y + v.z + v.w;
        s2 = fmaf(v.x, v.x, s2); s2 = fmaf(v.y, v.y, s2);
        s2 = fmaf(v.z, v.z, s2); s2 = fmaf(v.w, v.w, s2);
    }

    float4 gd4 = ((const float4*)gd)[l];
    float4 sel;
    sel.x = (gd4.x >= 0.f) ? vmax.x : vmin.x;
    sel.y = (gd4.y >= 0.f) ? vmax.y : vmin.y;
    sel.z = (gd4.z >= 0.f) ? vmax.z : vmin.z;
    sel.w = (gd4.w >= 0.f) ? vmax.w : vmin.w;
    psel[(size_t)gn * 64 + l] = sel;

    for (int off = 8; off; off >>= 1) {
        s1 += __shfl_down(s1, off, 64);
        s2 += __shfl_down(s2, off, 64);
    }
    if ((l & 15) == 0) {
        int g = l >> 4;
        atomicAdd(&a1[g], s1);
        atomicAdd(&a2[g], s2);
    }
    __syncthreads();
    if (t < GG) {
        atomicAdd(&st2[(b * GG + t) * 2 + 0], (double)a1[t]);
        atomicAdd(&st2[(b * GG + t) * 2 + 1], (double)a2[t]);
    }
}

// ---------------- mlp2: h2 = gelu(gn2(sel)), o = w2 @ h2 + b2, stats3 ----------------
// grid 256 blocks (1/CU), block 256 = 4 waves; block covers 32 n-columns, wave covers 8.
// Lane l owns output channel c = l (full K=256 dot per lane, no reduction).
// h2 kept in 8 float4 regs/lane (lane l holds m=4l..4l+3); K-loop broadcasts h2 via
// v_readlane (uniform index -> SGPR operand in v_fma). w2 staged in LDS, row stride 257
// so hot-loop reads hit banks (l+m)%32 -> 2-way (free).
__global__ __launch_bounds__(256, 4)
void k_mlp2(const float* __restrict__ psel,
            const float* __restrict__ w2, const float* __restrict__ b2,
            const float* __restrict__ gd, const float* __restrict__ bed,
            const double* __restrict__ st2, float* __restrict__ oraw, double* st3) {
    __shared__ float w2s[64 * 257];    // 64.25 KB

    int t = threadIdx.x;
    int w = t >> 6, l = t & 63;
    int b  = blockIdx.x >> 7;
    int n0 = (blockIdx.x & 127) * 32 + w * 8;   // this wave's 8 columns

    // stage w2 -> LDS [c][m] stride 257 (float4 global loads, scalar LDS writes)
    #pragma unroll
    for (int p = 0; p < 16; p++) {
        int i = p * 256 + t;                    // float4 index over w2 (4096 total)
        int c = i >> 6, mq = i & 63;
        float4 v = ((const float4*)w2)[i];
        float* dst = &w2s[c * 257 + mq * 4];
        dst[0] = v.x; dst[1] = v.y; dst[2] = v.z; dst[3] = v.w;
    }

    // gn2 affine params for this lane's 4 channels m = 4l..4l+3
    const double cnt2 = 64.0 * 4096.0 * 32.0;
    int g = l >> 4;
    double m_ = st2[(b * GG + g) * 2 + 0] / cnt2;
    double v_ = st2[(b * GG + g) * 2 + 1] / cnt2 - m_ * m_;
    float mean = (float)m_;
    float rstd = rsqrtf((float)v_ + EPSF);
    float4 gd4  = ((const float4*)gd)[l];
    float4 bed4 = ((const float4*)bed)[l];
    float ax = rstd * gd4.x, ay = rstd * gd4.y, az = rstd * gd4.z, aw = rstd * gd4.w;
    float cx = bed4.x - mean * ax, cy = bed4.y - mean * ay;
    float cz = bed4.z - mean * az, cw = bed4.w - mean * aw;

    // phase A: load psel for 8 columns, apply gn2+gelu -> h2 regs
    float4 h2r[8];
    #pragma unroll
    for (int j = 0; j < 8; j++) {
        float4 v = ((const float4*)psel)[((size_t)(b * NN) + n0 + j) * 64 + l];
        h2r[j].x = gelu_exact(fmaf(v.x, ax, cx));
        h2r[j].y = gelu_exact(fmaf(v.y, ay, cy));
        h2r[j].z = gelu_exact(fmaf(v.z, az, cz));
        h2r[j].w = gelu_exact(fmaf(v.w, aw, cw));
    }
    __syncthreads();

    // phase B: full K=256 dot per lane; c = l
    const float* w2l = &w2s[l * 257];
    float acc[8];
    #pragma unroll
    for (int j = 0; j < 8; j++) acc[j] = 0.f;

    #pragma unroll 8
    for (int mq = 0; mq < 64; mq++) {          // m = 4*mq + comp, broadcast from lane mq
        float w0 = w2l[4 * mq + 0];
        float w1_ = w2l[4 * mq + 1];
        float w2_ = w2l[4 * mq + 2];
        float w3_ = w2l[4 * mq + 3];
        #pragma unroll
        for (int j = 0; j < 8; j++) {
            acc[j] = fmaf(w0,  bcast_lane(h2r[j].x, mq), acc[j]);
            acc[j] = fmaf(w1_, bcast_lane(h2r[j].y, mq), acc[j]);
            acc[j] = fmaf(w2_, bcast_lane(h2r[j].z, mq), acc[j]);
            acc[j] = fmaf(w3_, bcast_lane(h2r[j].w, mq), acc[j]);
        }
    }

    float bias = b2[l];
    float so1 = 0.f, so2 = 0.f;
    #pragma unroll
    for (int j = 0; j < 8; j++) {
        acc[j] += bias;
        so1 += acc[j];
        so2 = fmaf(acc[j], acc[j], so2);
    }
    // store: lane l -> row c=l, 8 consecutive n (2 x float4 per lane)
    float* dst = &oraw[((size_t)(b * CC) + l) * NN + n0];
    *(float4*)&dst[0] = make_float4(acc[0], acc[1], acc[2], acc[3]);
    *(float4*)&dst[4] = make_float4(acc[4], acc[5], acc[6], acc[7]);

    // stats3 per c-group (g3 = l>>4): reduce within 16-lane segments
    so1 += __shfl_down(so1, 8, 16); so2 += __shfl_down(so2, 8, 16);
    so1 += __shfl_down(so1, 4, 16); so2 += __shfl_down(so2, 4, 16);
    so1 += __shfl_down(so1, 2, 16); so2 += __shfl_down(so2, 2, 16);
    so1 += __shfl_down(so1, 1, 16); so2 += __shfl_down(so2, 1, 16);
    if ((l & 15) == 0) {
        int g3 = l >> 4;
        atomicAdd(&st3[(b * GG + g3) * 2 + 0], (double)so1);
        atomicAdd(&st3[(b * GG + g3) * 2 + 1], (double)so2);
    }
}

// ---------------- final: gn3 + residual (float4) ----------------
// grid 512, block 256
__global__ void k_final(const float* __restrict__ oraw, const float* __restrict__ x,
                        const float* __restrict__ g2, const float* __restrict__ be2,
                        const double* __restrict__ st3, float* __restrict__ out) {
    int i4 = blockIdx.x * 256 + threadIdx.x;
    int base = i4 * 4;
    int c = (base >> 12) & 63;
    int b = base >> 18;
    int g = c >> 4;
    const double cnt = 16.0 * 4096.0;
    double mean_d = st3[(b * GG + g) * 2 + 0] / cnt;
    double var_d  = st3[(b * GG + g) * 2 + 1] / cnt - mean_d * mean_d;
    float mean = (float)mean_d;
    float rstd = rsqrtf((float)var_d + EPSF);
    float sc = rstd * g2[c];
    float ad = be2[c] - mean * sc;
    float4 o = ((const float4*)oraw)[i4];
    float4 xv = ((const float4*)x)[i4];
    float4 r;
    r.x = fmaf(o.x, sc, ad) + xv.x;
    r.y = fmaf(o.y, sc, ad) + xv.y;
    r.z = fmaf(o.z, sc, ad) + xv.z;
    r.w = fmaf(o.w, sc, ad) + xv.w;
    ((float4*)out)[i4] = r;
}

// ---------------- launch ----------------
extern "C" void kernel_launch(void* const* d_in, const int* in_sizes, int n_in,
                              void* d_out, int out_size, void* d_ws, size_t ws_size,
                              hipStream_t stream) {
    const float* x   = (const float*)d_in[0];
    const float* pos = (const float*)d_in[1];
    const float* w1  = (const float*)d_in[2];
    const float* b1  = (const float*)d_in[3];
    const float* g1  = (const float*)d_in[4];
    const float* be1 = (const float*)d_in[5];
    const float* wd  = (const float*)d_in[6];
    const float* gd  = (const float*)d_in[7];
    const float* bed = (const float*)d_in[8];
    const float* w2  = (const float*)d_in[9];
    const float* b2  = (const float*)d_in[10];
    const float* g2  = (const float*)d_in[11];
    const float* be2 = (const float*)d_in[12];
    float* out = (float*)d_out;

    float* ws = (float*)d_ws;
    const size_t SZ = (size_t)BB * MM * NN;
    float* h    = ws;
    float* p    = ws + SZ;
    float* psel = ws + 2 * SZ;
    float* oraw = ws + 3 * SZ;
    char* after = (char*)(oraw + (size_t)BB * CC * NN);
    int* idx = (int*)after;
    double* st = (double*)(after + (size_t)BB * NN * KK * sizeof(int));
    double* st1 = st;
    double* st2 = st + 16;
    double* st3 = st + 32;

    k_init<<<1, 64, 0, stream>>>(st);
    k_mlp1<<<512, 256, 0, stream>>>(x, w1, b1, h, st1);
    k_gn1t<<<dim3(64, 4, 2), 256, 0, stream>>>(h, g1, be1, wd, st1, p);
    k_ballq<<<2048, 256, 0, stream>>>(pos, idx);
    k_gather<<<2048, 256, 0, stream>>>((const float4*)p, idx, gd, (float4*)psel, st2);
    k_mlp2<<<256, 256, 0, stream>>>(psel, w2, b2, gd, bed, st2, oraw, st3);
    k_final<<<512, 256, 0, stream>>>(oraw, x, g2, be2, st3, out);
}

// Round 5
// 175.018 us; speedup vs baseline: 1.5007x; 1.1634x over previous
//
#include <hip/hip_runtime.h>
#include <hip/hip_fp16.h>
#include <math.h>

#define BB 2
#define CC 64
#define NN 4096
#define MM 256
#define KK 32
#define GG 4
#define EPSF 1e-5f

__device__ __forceinline__ float gelu_exact(float x) {
    return 0.5f * x * (1.0f + erff(x * 0.70710678118654752f));
}

__device__ __forceinline__ unsigned pkmax(unsigned a, unsigned b) {
    unsigned d;
    asm volatile("v_pk_max_f16 %0, %1, %2" : "=v"(d) : "v"(a), "v"(b));
    return d;
}
__device__ __forceinline__ unsigned pkmin(unsigned a, unsigned b) {
    unsigned d;
    asm volatile("v_pk_min_f16 %0, %1, %2" : "=v"(d) : "v"(a), "v"(b));
    return d;
}
__device__ __forceinline__ unsigned selpair(unsigned mx, unsigned mn, float g0, float g1) {
    unsigned lo = (g0 >= 0.f) ? (mx & 0x0000FFFFu) : (mn & 0x0000FFFFu);
    unsigned hi = (g1 >= 0.f) ? (mx & 0xFFFF0000u) : (mn & 0xFFFF0000u);
    return lo | hi;
}

// ---------------- init: zero the 48 stat doubles ----------------
__global__ void k_init(double* st) {
    int t = threadIdx.x;
    if (t < 48) st[t] = 0.0;
}

// ---------------- mlp1: h = w1 @ x + b1, accumulate stats1 ----------------
// grid 512 = B(2) x MT(8 tiles of 32 m) x NT(32 tiles of 128 n), block 256
__global__ void k_mlp1(const float* __restrict__ x, const float* __restrict__ w1,
                       const float* __restrict__ b1, float* __restrict__ h, double* st1) {
    __shared__ float xs[64 * 128];
    __shared__ float w1t[64 * 32];
    __shared__ float r1[4], r2[4];

    int bx = blockIdx.x;
    int nt = bx & 31, mt = (bx >> 5) & 7, b = bx >> 8;
    int n0 = nt * 128, m0 = mt * 32;
    int t = threadIdx.x;

    {
        int nq = t & 31, ch = t >> 5;
        #pragma unroll
        for (int p = 0; p < 8; p++) {
            int c = p * 8 + ch;
            float4 v = *(const float4*)&x[((size_t)(b * CC + c)) * NN + n0 + nq * 4];
            *(float4*)&xs[c * 128 + nq * 4] = v;
        }
    }
    {
        #pragma unroll
        for (int p = 0; p < 2; p++) {
            int idx = p * 256 + t;
            int m = idx >> 4, cq = idx & 15;
            float4 v = *(const float4*)&w1[(m0 + m) * CC + cq * 4];
            w1t[(cq * 4 + 0) * 32 + m] = v.x;
            w1t[(cq * 4 + 1) * 32 + m] = v.y;
            w1t[(cq * 4 + 2) * 32 + m] = v.z;
            w1t[(cq * 4 + 3) * 32 + m] = v.w;
        }
    }
    __syncthreads();

    int nq = t & 31;
    int mseg = t >> 5;
    float o[4][4];
    #pragma unroll
    for (int i = 0; i < 4; i++)
        #pragma unroll
        for (int j = 0; j < 4; j++) o[i][j] = 0.f;

    for (int c = 0; c < 64; c++) {
        float4 xv = *(float4*)&xs[c * 128 + nq * 4];
        float4 wv = *(float4*)&w1t[c * 32 + mseg * 4];
        o[0][0] = fmaf(wv.x, xv.x, o[0][0]); o[0][1] = fmaf(wv.x, xv.y, o[0][1]);
        o[0][2] = fmaf(wv.x, xv.z, o[0][2]); o[0][3] = fmaf(wv.x, xv.w, o[0][3]);
        o[1][0] = fmaf(wv.y, xv.x, o[1][0]); o[1][1] = fmaf(wv.y, xv.y, o[1][1]);
        o[1][2] = fmaf(wv.y, xv.z, o[1][2]); o[1][3] = fmaf(wv.y, xv.w, o[1][3]);
        o[2][0] = fmaf(wv.z, xv.x, o[2][0]); o[2][1] = fmaf(wv.z, xv.y, o[2][1]);
        o[2][2] = fmaf(wv.z, xv.z, o[2][2]); o[2][3] = fmaf(wv.z, xv.w, o[2][3]);
        o[3][0] = fmaf(wv.w, xv.x, o[3][0]); o[3][1] = fmaf(wv.w, xv.y, o[3][1]);
        o[3][2] = fmaf(wv.w, xv.z, o[3][2]); o[3][3] = fmaf(wv.w, xv.w, o[3][3]);
    }

    float s1 = 0.f, s2 = 0.f;
    #pragma unroll
    for (int mi = 0; mi < 4; mi++) {
        int m = m0 + mseg * 4 + mi;
        float bv = b1[m];
        float4 r;
        r.x = o[mi][0] + bv; r.y = o[mi][1] + bv;
        r.z = o[mi][2] + bv; r.w = o[mi][3] + bv;
        *(float4*)&h[((size_t)(b * MM + m)) * NN + n0 + nq * 4] = r;
        s1 += r.x + r.y + r.z + r.w;
        s2 = fmaf(r.x, r.x, s2); s2 = fmaf(r.y, r.y, s2);
        s2 = fmaf(r.z, r.z, s2); s2 = fmaf(r.w, r.w, s2);
    }
    for (int off = 32; off; off >>= 1) {
        s1 += __shfl_down(s1, off, 64);
        s2 += __shfl_down(s2, off, 64);
    }
    int w = t >> 6, l = t & 63;
    if (l == 0) { r1[w] = s1; r2[w] = s2; }
    __syncthreads();
    if (t == 0) {
        float ts1 = r1[0] + r1[1] + r1[2] + r1[3];
        float ts2 = r2[0] + r2[1] + r2[2] + r2[3];
        int g = m0 >> 6;
        atomicAdd(&st1[(b * GG + g) * 2 + 0], (double)ts1);
        atomicAdd(&st1[(b * GG + g) * 2 + 1], (double)ts2);
    }
}

// ---------------- gn1 + gelu + wd -> fp16 p[b][n][m], + per-row group sums R ----------------
// grid (N/64, M/64, B), block 256. R[b][n][8] = {R1 g0..g3, R2 g0..g3}; this block's
// group == blockIdx.y so each (n,g) cell is owned by exactly one block (plain stores).
__global__ void k_gn1t(const float* __restrict__ h, const float* __restrict__ g1,
                       const float* __restrict__ be1, const float* __restrict__ wd,
                       const double* __restrict__ st1, __half* __restrict__ pH,
                       float* __restrict__ R) {
    int n0 = blockIdx.x * 64;
    int m0 = blockIdx.y * 64;
    int b  = blockIdx.z;
    int g  = m0 >> 6;
    double s1 = st1[(b * GG + g) * 2 + 0];
    double s2 = st1[(b * GG + g) * 2 + 1];
    const double cnt = 64.0 * 4096.0;
    double mean_d = s1 / cnt;
    double var_d  = s2 / cnt - mean_d * mean_d;
    float mean = (float)mean_d;
    float rstd = rsqrtf((float)var_d + EPSF);

    __shared__ float tile[64 * 65];
    int t = threadIdx.x;
    int nq = t & 15, mr = t >> 4;
    #pragma unroll
    for (int pp = 0; pp < 4; pp++) {
        int row = pp * 16 + mr;
        int m = m0 + row;
        float a = rstd * g1[m];
        float cc2 = be1[m] - mean * a;
        float wdm = wd[m];
        float4 hv = *(const float4*)&h[((size_t)(b * MM + m)) * NN + n0 + nq * 4];
        tile[row * 65 + nq * 4 + 0] = gelu_exact(fmaf(hv.x, a, cc2)) * wdm;
        tile[row * 65 + nq * 4 + 1] = gelu_exact(fmaf(hv.y, a, cc2)) * wdm;
        tile[row * 65 + nq * 4 + 2] = gelu_exact(fmaf(hv.z, a, cc2)) * wdm;
        tile[row * 65 + nq * 4 + 3] = gelu_exact(fmaf(hv.w, a, cc2)) * wdm;
    }
    __syncthreads();
    #pragma unroll
    for (int pp = 0; pp < 4; pp++) {
        int id = pp * 256 + t;
        int nl = id >> 4, mq = id & 15;
        float a0 = tile[(mq * 4 + 0) * 65 + nl];
        float a1 = tile[(mq * 4 + 1) * 65 + nl];
        float a2 = tile[(mq * 4 + 2) * 65 + nl];
        float a3 = tile[(mq * 4 + 3) * 65 + nl];
        __half2 hA = __float22half2_rn(make_float2(a0, a1));
        __half2 hB = __float22half2_rn(make_float2(a2, a3));
        uint2 st8;
        st8.x = *(unsigned*)&hA; st8.y = *(unsigned*)&hB;
        *(uint2*)((char*)pH + ((((size_t)(b * NN) + n0 + nl)) << 9) + (m0 + mq * 4) * 2) = st8;
        // stats from the fp16-rounded values (matches what downstream reads)
        float2 fa = __half22float2(hA);
        float2 fb = __half22float2(hB);
        float t1 = fa.x + fa.y + fb.x + fb.y;
        float t2 = fa.x * fa.x + fa.y * fa.y + fb.x * fb.x + fb.y * fb.y;
        #pragma unroll
        for (int off = 8; off; off >>= 1) {
            t1 += __shfl_down(t1, off, 16);
            t2 += __shfl_down(t2, off, 16);
        }
        if ((t & 15) == 0) {
            float* rr = &R[((size_t)(b * NN) + n0 + nl) * 8];
            rr[g]     = t1;
            rr[4 + g] = t2;
        }
    }
}

// ---------------- ball query: one wave per query point ----------------
// grid 2048, block 256 (4 waves)
__global__ void k_ballq(const float* __restrict__ pos, int* __restrict__ idx) {
    int wid  = blockIdx.x * 4 + (threadIdx.x >> 6);
    int lane = threadIdx.x & 63;
    int b = wid >> 12;
    int n = wid & 4095;
    const float* px = pos + b * 3 * NN;
    const float* py = px + NN;
    const float* pz = py + NN;
    float qx = px[n], qy = py[n], qz = pz[n];
    float qsq = qx*qx + qy*qy + qz*qz;
    int* row = idx + (b * NN + n) * KK;

    int found = 0;
    int first = -1;
    const float R2 = 0.04f;
    for (int m0 = 0; m0 < NN && found < KK; m0 += 64) {
        int m = m0 + lane;
        float ax = px[m], ay = py[m], az = pz[m];
        float msq = ax*ax + ay*ay + az*az;
        float dot = qx*ax + qy*ay + qz*az;
        float d = qsq + msq - 2.0f * dot;
        bool hit = !(d > R2);
        unsigned long long mask = __ballot(hit);
        if (first < 0 && mask) first = m0 + (__ffsll((long long)mask) - 1);
        unsigned long long lt = (lane == 0) ? 0ULL : (mask & ((1ULL << lane) - 1ULL));
        int posh = __popcll(lt);
        if (hit && (found + posh) < KK) row[found + posh] = m;
        found += __popcll(mask);
        if (found > KK) found = KK;
    }
    if (lane < KK && lane >= found) row[lane] = first;
}

// ---------------- gstats: st2 = sum over points/neighbors of R rows ----------------
// grid 256 blocks, block 256; block covers 32 points (8 half-waves x 4 iters).
__global__ void k_gstats(const int* __restrict__ idx, const float* __restrict__ R,
                         double* st2) {
    __shared__ float acc[8];
    int t = threadIdx.x;
    if (t < 8) acc[t] = 0.f;
    __syncthreads();
    int hw = t >> 5, cl = t & 31;
    int pbase = blockIdx.x * 32;
    int b = pbase >> 12;
    float s[8];
    #pragma unroll
    for (int c = 0; c < 8; c++) s[c] = 0.f;
    #pragma unroll
    for (int it = 0; it < 4; it++) {
        int pt = pbase + it * 8 + hw;
        int j = idx[pt * KK + cl];
        const float* rr = &R[((size_t)(b * NN) + j) * 8];
        float4 ra = *(const float4*)rr;
        float4 rb = *(const float4*)(rr + 4);
        s[0] += ra.x; s[1] += ra.y; s[2] += ra.z; s[3] += ra.w;
        s[4] += rb.x; s[5] += rb.y; s[6] += rb.z; s[7] += rb.w;
    }
    #pragma unroll
    for (int off = 16; off; off >>= 1) {
        #pragma unroll
        for (int c = 0; c < 8; c++) s[c] += __shfl_down(s[c], off, 32);
    }
    if (cl == 0) {
        #pragma unroll
        for (int c = 0; c < 8; c++) atomicAdd(&acc[c], s[c]);
    }
    __syncthreads();
    if (t < 8) {
        int g = t & 3, isR2 = t >> 2;
        atomicAdd(&st2[(b * GG + g) * 2 + isR2], (double)acc[t]);
    }
}

// ---------------- gather: fp16, 2 neighbors per 16B/lane load, packed max/min ----------------
// grid 2048 blocks, 256 threads; wave w -> point gn = blockIdx.x*4 + w.
// half h=l>>5 handles neighbors 2k+h; lane cl=l&31 handles channels 8cl..8cl+7.
__global__ __launch_bounds__(256)
void k_gather(const __half* __restrict__ pH, const int* __restrict__ idx,
              const float* __restrict__ gd, __half* __restrict__ pselH) {
    int t = threadIdx.x;
    int w = t >> 6, l = t & 63;
    int gn = blockIdx.x * 4 + w;
    int b = gn >> 12;
    int h = l >> 5, cl = l & 31;
    int myidx = idx[gn * KK + cl];
    const char* pb = (const char*)(pH + (size_t)b * NN * 256);
    int laneoff = cl * 16;

    unsigned vmax0 = 0xFC00FC00u, vmax1 = 0xFC00FC00u, vmax2 = 0xFC00FC00u, vmax3 = 0xFC00FC00u;
    unsigned vmin0 = 0x7C007C00u, vmin1 = 0x7C007C00u, vmin2 = 0x7C007C00u, vmin3 = 0x7C007C00u;

    #pragma unroll
    for (int k = 0; k < 16; k++) {
        int ja = __shfl(myidx, 2 * k, 64);
        int jb = __shfl(myidx, 2 * k + 1, 64);
        int j = h ? jb : ja;
        uint4 raw = *(const uint4*)(pb + (((size_t)j) << 9) + laneoff);
        vmax0 = pkmax(vmax0, raw.x); vmin0 = pkmin(vmin0, raw.x);
        vmax1 = pkmax(vmax1, raw.y); vmin1 = pkmin(vmin1, raw.y);
        vmax2 = pkmax(vmax2, raw.z); vmin2 = pkmin(vmin2, raw.z);
        vmax3 = pkmax(vmax3, raw.w); vmin3 = pkmin(vmin3, raw.w);
    }
    // merge the two halves (each covered 16 of the 32 neighbors)
    vmax0 = pkmax(vmax0, (unsigned)__shfl_xor((int)vmax0, 32, 64));
    vmax1 = pkmax(vmax1, (unsigned)__shfl_xor((int)vmax1, 32, 64));
    vmax2 = pkmax(vmax2, (unsigned)__shfl_xor((int)vmax2, 32, 64));
    vmax3 = pkmax(vmax3, (unsigned)__shfl_xor((int)vmax3, 32, 64));
    vmin0 = pkmin(vmin0, (unsigned)__shfl_xor((int)vmin0, 32, 64));
    vmin1 = pkmin(vmin1, (unsigned)__shfl_xor((int)vmin1, 32, 64));
    vmin2 = pkmin(vmin2, (unsigned)__shfl_xor((int)vmin2, 32, 64));
    vmin3 = pkmin(vmin3, (unsigned)__shfl_xor((int)vmin3, 32, 64));

    if (h == 0) {
        const float4* g4 = (const float4*)gd;   // channels 8cl..8cl+7
        float4 gA = g4[cl * 2], gB = g4[cl * 2 + 1];
        uint4 out;
        out.x = selpair(vmax0, vmin0, gA.x, gA.y);
        out.y = selpair(vmax1, vmin1, gA.z, gA.w);
        out.z = selpair(vmax2, vmin2, gB.x, gB.y);
        out.w = selpair(vmax3, vmin3, gB.z, gB.w);
        *(uint4*)((char*)pselH + (((size_t)gn) << 9) + laneoff) = out;
    }
}

// ---------------- mlp2: h2 = gelu(gn2(sel)), o = w2 @ h2 + b2, stats3 ----------------
// grid 256 blocks, block 256 = 4 waves; lane l owns output channel c = l.
__global__ __launch_bounds__(256, 4)
void k_mlp2(const __half* __restrict__ pselH,
            const float* __restrict__ w2, const float* __restrict__ b2,
            const float* __restrict__ gd, const float* __restrict__ bed,
            const double* __restrict__ st2, float* __restrict__ oraw, double* st3) {
    __shared__ float w2s[64 * 257];

    int t = threadIdx.x;
    int w = t >> 6, l = t & 63;
    int b  = blockIdx.x >> 7;
    int n0 = (blockIdx.x & 127) * 32 + w * 8;

    #pragma unroll
    for (int p = 0; p < 16; p++) {
        int i = p * 256 + t;
        int c = i >> 6, mq = i & 63;
        float4 v = ((const float4*)w2)[i];
        float* dst = &w2s[c * 257 + mq * 4];
        dst[0] = v.x; dst[1] = v.y; dst[2] = v.z; dst[3] = v.w;
    }

    const double cnt2 = 64.0 * 4096.0 * 32.0;
    int g = l >> 4;
    double m_ = st2[(b * GG + g) * 2 + 0] / cnt2;
    double v_ = st2[(b * GG + g) * 2 + 1] / cnt2 - m_ * m_;
    float mean = (float)m_;
    float rstd = rsqrtf((float)v_ + EPSF);
    float4 gd4  = ((const float4*)gd)[l];
    float4 bed4 = ((const float4*)bed)[l];
    float ax = rstd * gd4.x, ay = rstd * gd4.y, az = rstd * gd4.z, aw = rstd * gd4.w;
    float cx = bed4.x - mean * ax, cy = bed4.y - mean * ay;
    float cz = bed4.z - mean * az, cw = bed4.w - mean * aw;

    float4 h2r[8];
    #pragma unroll
    for (int j = 0; j < 8; j++) {
        uint2 raw = *(const uint2*)((const char*)pselH +
                     ((((size_t)(b * NN)) + n0 + j) << 9) + l * 8);
        float2 fa = __half22float2(*(__half2*)&raw.x);
        float2 fb = __half22float2(*(__half2*)&raw.y);
        h2r[j].x = gelu_exact(fmaf(fa.x, ax, cx));
        h2r[j].y = gelu_exact(fmaf(fa.y, ay, cy));
        h2r[j].z = gelu_exact(fmaf(fb.x, az, cz));
        h2r[j].w = gelu_exact(fmaf(fb.y, aw, cw));
    }
    __syncthreads();

    const float* w2l = &w2s[l * 257];
    float acc[8];
    #pragma unroll
    for (int j = 0; j < 8; j++) acc[j] = 0.f;

    #pragma unroll 8
    for (int mq = 0; mq < 64; mq++) {
        float w0 = w2l[4 * mq + 0];
        float w1_ = w2l[4 * mq + 1];
        float w2_ = w2l[4 * mq + 2];
        float w3_ = w2l[4 * mq + 3];
        #pragma unroll
        for (int j = 0; j < 8; j++) {
            acc[j] = fmaf(w0,  __int_as_float(__builtin_amdgcn_readlane(__float_as_int(h2r[j].x), mq)), acc[j]);
            acc[j] = fmaf(w1_, __int_as_float(__builtin_amdgcn_readlane(__float_as_int(h2r[j].y), mq)), acc[j]);
            acc[j] = fmaf(w2_, __int_as_float(__builtin_amdgcn_readlane(__float_as_int(h2r[j].z), mq)), acc[j]);
            acc[j] = fmaf(w3_, __int_as_float(__builtin_amdgcn_readlane(__float_as_int(h2r[j].w), mq)), acc[j]);
        }
    }

    float bias = b2[l];
    float so1 = 0.f, so2 = 0.f;
    #pragma unroll
    for (int j = 0; j < 8; j++) {
        acc[j] += bias;
        so1 += acc[j];
        so2 = fmaf(acc[j], acc[j], so2);
    }
    float* dst = &oraw[((size_t)(b * CC) + l) * NN + n0];
    *(float4*)&dst[0] = make_float4(acc[0], acc[1], acc[2], acc[3]);
    *(float4*)&dst[4] = make_float4(acc[4], acc[5], acc[6], acc[7]);

    so1 += __shfl_down(so1, 8, 16); so2 += __shfl_down(so2, 8, 16);
    so1 += __shfl_down(so1, 4, 16); so2 += __shfl_down(so2, 4, 16);
    so1 += __shfl_down(so1, 2, 16); so2 += __shfl_down(so2, 2, 16);
    so1 += __shfl_down(so1, 1, 16); so2 += __shfl_down(so2, 1, 16);
    if ((l & 15) == 0) {
        int g3 = l >> 4;
        atomicAdd(&st3[(b * GG + g3) * 2 + 0], (double)so1);
        atomicAdd(&st3[(b * GG + g3) * 2 + 1], (double)so2);
    }
}

// ---------------- final: gn3 + residual (float4) ----------------
// grid 512, block 256
__global__ void k_final(const float* __restrict__ oraw, const float* __restrict__ x,
                        const float* __restrict__ g2, const float* __restrict__ be2,
                        const double* __restrict__ st3, float* __restrict__ out) {
    int i4 = blockIdx.x * 256 + threadIdx.x;
    int base = i4 * 4;
    int c = (base >> 12) & 63;
    int b = base >> 18;
    int g = c >> 4;
    const double cnt = 16.0 * 4096.0;
    double mean_d = st3[(b * GG + g) * 2 + 0] / cnt;
    double var_d  = st3[(b * GG + g) * 2 + 1] / cnt - mean_d * mean_d;
    float mean = (float)mean_d;
    float rstd = rsqrtf((float)var_d + EPSF);
    float sc = rstd * g2[c];
    float ad = be2[c] - mean * sc;
    float4 o = ((const float4*)oraw)[i4];
    float4 xv = ((const float4*)x)[i4];
    float4 r;
    r.x = fmaf(o.x, sc, ad) + xv.x;
    r.y = fmaf(o.y, sc, ad) + xv.y;
    r.z = fmaf(o.z, sc, ad) + xv.z;
    r.w = fmaf(o.w, sc, ad) + xv.w;
    ((float4*)out)[i4] = r;
}

// ---------------- launch ----------------
extern "C" void kernel_launch(void* const* d_in, const int* in_sizes, int n_in,
                              void* d_out, int out_size, void* d_ws, size_t ws_size,
                              hipStream_t stream) {
    const float* x   = (const float*)d_in[0];
    const float* pos = (const float*)d_in[1];
    const float* w1  = (const float*)d_in[2];
    const float* b1  = (const float*)d_in[3];
    const float* g1  = (const float*)d_in[4];
    const float* be1 = (const float*)d_in[5];
    const float* wd  = (const float*)d_in[6];
    const float* gd  = (const float*)d_in[7];
    const float* bed = (const float*)d_in[8];
    const float* w2  = (const float*)d_in[9];
    const float* b2  = (const float*)d_in[10];
    const float* g2  = (const float*)d_in[11];
    const float* be2 = (const float*)d_in[12];
    float* out = (float*)d_out;

    char* wsb = (char*)d_ws;
    float*  h     = (float*)wsb;                               // 8 MB
    __half* pH    = (__half*)(wsb + 8388608);                  // 4 MB
    __half* pselH = (__half*)(wsb + 12582912);                 // 4 MB
    float*  oraw  = (float*)(wsb + 16777216);                  // 2 MB
    int*    idx   = (int*)(wsb + 18874368);                    // 1 MB
    float*  R     = (float*)(wsb + 19922944);                  // 256 KB
    double* st    = (double*)(wsb + 20185088);                 // 384 B
    double* st1 = st;
    double* st2 = st + 16;
    double* st3 = st + 32;

    k_init<<<1, 64, 0, stream>>>(st);
    k_mlp1<<<512, 256, 0, stream>>>(x, w1, b1, h, st1);
    k_gn1t<<<dim3(64, 4, 2), 256, 0, stream>>>(h, g1, be1, wd, st1, pH, R);
    k_ballq<<<2048, 256, 0, stream>>>(pos, idx);
    k_gstats<<<256, 256, 0, stream>>>(idx, R, st2);
    k_gather<<<2048, 256, 0, stream>>>(pH, idx, gd, pselH);
    k_mlp2<<<256, 256, 0, stream>>>(pselH, w2, b2, gd, bed, st2, oraw, st3);
    k_final<<<512, 256, 0, stream>>>(oraw, x, g2, be2, st3, out);
}

// Round 7
// 155.722 us; speedup vs baseline: 1.6867x; 1.1239x over previous
//
#include <hip/hip_runtime.h>
#include <hip/hip_fp16.h>
#include <math.h>

#define BB 2
#define CC 64
#define NN 4096
#define MM 256
#define KK 32
#define GG 4
#define EPSF 1e-5f

__device__ __forceinline__ float gelu_exact(float x) {
    return 0.5f * x * (1.0f + erff(x * 0.70710678118654752f));
}

__device__ __forceinline__ unsigned pkmax(unsigned a, unsigned b) {
    unsigned d;
    asm volatile("v_pk_max_f16 %0, %1, %2" : "=v"(d) : "v"(a), "v"(b));
    return d;
}
__device__ __forceinline__ unsigned pkmin(unsigned a, unsigned b) {
    unsigned d;
    asm volatile("v_pk_min_f16 %0, %1, %2" : "=v"(d) : "v"(a), "v"(b));
    return d;
}
__device__ __forceinline__ unsigned selpair(unsigned mx, unsigned mn, float g0, float g1) {
    unsigned lo = (g0 >= 0.f) ? (mx & 0x0000FFFFu) : (mn & 0x0000FFFFu);
    unsigned hi = (g1 >= 0.f) ? (mx & 0xFFFF0000u) : (mn & 0xFFFF0000u);
    return lo | hi;
}
__device__ __forceinline__ float bcast_lane(float v, int lane) {
    return __int_as_float(__builtin_amdgcn_readlane(__float_as_int(v), lane));
}

// ---------------- mlp1: h = w1 @ x + b1, per-block stats partials ----------------
// grid 512 = B(2) x MT(8 tiles of 32 m) x NT(32 tiles of 128 n), block 256
__global__ void k_mlp1(const float* __restrict__ x, const float* __restrict__ w1,
                       const float* __restrict__ b1, float* __restrict__ h,
                       float2* __restrict__ Mp) {
    __shared__ float xs[64 * 128];
    __shared__ float w1t[64 * 32];
    __shared__ float r1[4], r2[4];

    int bx = blockIdx.x;
    int nt = bx & 31, mt = (bx >> 5) & 7, b = bx >> 8;
    int n0 = nt * 128, m0 = mt * 32;
    int t = threadIdx.x;

    {
        int nq = t & 31, ch = t >> 5;
        #pragma unroll
        for (int p = 0; p < 8; p++) {
            int c = p * 8 + ch;
            float4 v = *(const float4*)&x[((size_t)(b * CC + c)) * NN + n0 + nq * 4];
            *(float4*)&xs[c * 128 + nq * 4] = v;
        }
    }
    {
        #pragma unroll
        for (int p = 0; p < 2; p++) {
            int idx = p * 256 + t;
            int m = idx >> 4, cq = idx & 15;
            float4 v = *(const float4*)&w1[(m0 + m) * CC + cq * 4];
            w1t[(cq * 4 + 0) * 32 + m] = v.x;
            w1t[(cq * 4 + 1) * 32 + m] = v.y;
            w1t[(cq * 4 + 2) * 32 + m] = v.z;
            w1t[(cq * 4 + 3) * 32 + m] = v.w;
        }
    }
    __syncthreads();

    int nq = t & 31;
    int mseg = t >> 5;
    float o[4][4];
    #pragma unroll
    for (int i = 0; i < 4; i++)
        #pragma unroll
        for (int j = 0; j < 4; j++) o[i][j] = 0.f;

    for (int c = 0; c < 64; c++) {
        float4 xv = *(float4*)&xs[c * 128 + nq * 4];
        float4 wv = *(float4*)&w1t[c * 32 + mseg * 4];
        o[0][0] = fmaf(wv.x, xv.x, o[0][0]); o[0][1] = fmaf(wv.x, xv.y, o[0][1]);
        o[0][2] = fmaf(wv.x, xv.z, o[0][2]); o[0][3] = fmaf(wv.x, xv.w, o[0][3]);
        o[1][0] = fmaf(wv.y, xv.x, o[1][0]); o[1][1] = fmaf(wv.y, xv.y, o[1][1]);
        o[1][2] = fmaf(wv.y, xv.z, o[1][2]); o[1][3] = fmaf(wv.y, xv.w, o[1][3]);
        o[2][0] = fmaf(wv.z, xv.x, o[2][0]); o[2][1] = fmaf(wv.z, xv.y, o[2][1]);
        o[2][2] = fmaf(wv.z, xv.z, o[2][2]); o[2][3] = fmaf(wv.z, xv.w, o[2][3]);
        o[3][0] = fmaf(wv.w, xv.x, o[3][0]); o[3][1] = fmaf(wv.w, xv.y, o[3][1]);
        o[3][2] = fmaf(wv.w, xv.z, o[3][2]); o[3][3] = fmaf(wv.w, xv.w, o[3][3]);
    }

    float s1 = 0.f, s2 = 0.f;
    #pragma unroll
    for (int mi = 0; mi < 4; mi++) {
        int m = m0 + mseg * 4 + mi;
        float bv = b1[m];
        float4 r;
        r.x = o[mi][0] + bv; r.y = o[mi][1] + bv;
        r.z = o[mi][2] + bv; r.w = o[mi][3] + bv;
        *(float4*)&h[((size_t)(b * MM + m)) * NN + n0 + nq * 4] = r;
        s1 += r.x + r.y + r.z + r.w;
        s2 = fmaf(r.x, r.x, s2); s2 = fmaf(r.y, r.y, s2);
        s2 = fmaf(r.z, r.z, s2); s2 = fmaf(r.w, r.w, s2);
    }
    for (int off = 32; off; off >>= 1) {
        s1 += __shfl_down(s1, off, 64);
        s2 += __shfl_down(s2, off, 64);
    }
    int w = t >> 6, l = t & 63;
    if (l == 0) { r1[w] = s1; r2[w] = s2; }
    __syncthreads();
    if (t == 0) {
        Mp[bx] = make_float2(r1[0] + r1[1] + r1[2] + r1[3],
                             r2[0] + r2[1] + r2[2] + r2[3]);
    }
}

// ---------------- gn1 + gelu + wd -> fp16 p[b][n][m], + per-row group sums R ----------------
// grid (N/64, M/64=G, B), block 256. Stats1 reduced from Mp partials (wave 0).
__global__ void k_gn1t(const float* __restrict__ h, const float* __restrict__ g1,
                       const float* __restrict__ be1, const float* __restrict__ wd,
                       const float2* __restrict__ Mp, __half* __restrict__ pH,
                       float* __restrict__ R) {
    __shared__ float tile[64 * 65];
    __shared__ float mv[2];
    int n0 = blockIdx.x * 64;
    int m0 = blockIdx.y * 64;
    int b  = blockIdx.z;
    int g  = blockIdx.y;
    int t = threadIdx.x;

    if (t < 64) {
        float2 p2 = Mp[b * 256 + g * 64 + t];   // mt in {2g,2g+1} x nt 0..31 contiguous
        float s1 = p2.x, s2 = p2.y;
        for (int off = 32; off; off >>= 1) {
            s1 += __shfl_down(s1, off, 64);
            s2 += __shfl_down(s2, off, 64);
        }
        if (t == 0) {
            const double cnt = 64.0 * 4096.0;
            double md = (double)s1 / cnt;
            double vd = (double)s2 / cnt - md * md;
            mv[0] = (float)md;
            mv[1] = rsqrtf((float)vd + EPSF);
        }
    }
    __syncthreads();
    float mean = mv[0], rstd = mv[1];

    int nq = t & 15, mr = t >> 4;
    #pragma unroll
    for (int pp = 0; pp < 4; pp++) {
        int row = pp * 16 + mr;
        int m = m0 + row;
        float a = rstd * g1[m];
        float cc2 = be1[m] - mean * a;
        float wdm = wd[m];
        float4 hv = *(const float4*)&h[((size_t)(b * MM + m)) * NN + n0 + nq * 4];
        tile[row * 65 + nq * 4 + 0] = gelu_exact(fmaf(hv.x, a, cc2)) * wdm;
        tile[row * 65 + nq * 4 + 1] = gelu_exact(fmaf(hv.y, a, cc2)) * wdm;
        tile[row * 65 + nq * 4 + 2] = gelu_exact(fmaf(hv.z, a, cc2)) * wdm;
        tile[row * 65 + nq * 4 + 3] = gelu_exact(fmaf(hv.w, a, cc2)) * wdm;
    }
    __syncthreads();
    #pragma unroll
    for (int pp = 0; pp < 4; pp++) {
        int id = pp * 256 + t;
        int nl = id >> 4, mq = id & 15;
        float a0 = tile[(mq * 4 + 0) * 65 + nl];
        float a1 = tile[(mq * 4 + 1) * 65 + nl];
        float a2 = tile[(mq * 4 + 2) * 65 + nl];
        float a3 = tile[(mq * 4 + 3) * 65 + nl];
        __half2 hA = __float22half2_rn(make_float2(a0, a1));
        __half2 hB = __float22half2_rn(make_float2(a2, a3));
        uint2 st8;
        st8.x = *(unsigned*)&hA; st8.y = *(unsigned*)&hB;
        *(uint2*)((char*)pH + ((((size_t)(b * NN) + n0 + nl)) << 9) + (m0 + mq * 4) * 2) = st8;
        float2 fa = __half22float2(hA);
        float2 fb = __half22float2(hB);
        float t1 = fa.x + fa.y + fb.x + fb.y;
        float t2 = fa.x * fa.x + fa.y * fa.y + fb.x * fb.x + fb.y * fb.y;
        #pragma unroll
        for (int off = 8; off; off >>= 1) {
            t1 += __shfl_down(t1, off, 16);
            t2 += __shfl_down(t2, off, 16);
        }
        if ((t & 15) == 0) {
            float* rr = &R[((size_t)(b * NN) + n0 + nl) * 8];
            rr[g]     = t1;
            rr[4 + g] = t2;
        }
    }
}

// ---------------- ball query: one wave per query point ----------------
// grid 2048, block 256 (4 waves)
// NOTE: source byte-identical to R1-R5 (5x passing). The distance expression
// tree (msq/dot/d as separate statements) determines fma contraction; do NOT
// rewrite it — R6 inlined a re-associated form and a radius-boundary point
// flipped its neighbor set (absmax 0.199 fail).
__global__ void k_ballq(const float* __restrict__ pos, int* __restrict__ idx) {
    int wid  = blockIdx.x * 4 + (threadIdx.x >> 6);
    int lane = threadIdx.x & 63;
    int b = wid >> 12;
    int n = wid & 4095;
    const float* px = pos + b * 3 * NN;
    const float* py = px + NN;
    const float* pz = py + NN;
    float qx = px[n], qy = py[n], qz = pz[n];
    float qsq = qx*qx + qy*qy + qz*qz;
    int* row = idx + (b * NN + n) * KK;

    int found = 0;
    int first = -1;
    const float R2 = 0.04f;
    for (int m0 = 0; m0 < NN && found < KK; m0 += 64) {
        int m = m0 + lane;
        float ax = px[m], ay = py[m], az = pz[m];
        float msq = ax*ax + ay*ay + az*az;
        float dot = qx*ax + qy*ay + qz*az;
        float d = qsq + msq - 2.0f * dot;
        bool hit = !(d > R2);
        unsigned long long mask = __ballot(hit);
        if (first < 0 && mask) first = m0 + (__ffsll((long long)mask) - 1);
        unsigned long long lt = (lane == 0) ? 0ULL : (mask & ((1ULL << lane) - 1ULL));
        int posh = __popcll(lt);
        if (hit && (found + posh) < KK) row[found + posh] = m;
        found += __popcll(mask);
        if (found > KK) found = KK;
    }
    if (lane < KK && lane >= found) row[lane] = first;
}

// ---------------- gather + neighbor-stats (reads idx from global) ----------------
// grid 2048 blocks, 256 threads; wave w -> point gn = blockIdx.x*4 + w.
// Lower 32 lanes store psel; upper 32 lanes sum R rows over the 32 neighbors -> Rp.
__global__ __launch_bounds__(256)
void k_qgather(const __half* __restrict__ pH, const int* __restrict__ idx,
               const float* __restrict__ R, const float* __restrict__ gd,
               __half* __restrict__ pselH, float* __restrict__ Rp) {
    int t = threadIdx.x, w = t >> 6, l = t & 63;
    int gn = blockIdx.x * 4 + w;
    int b = gn >> 12;

    int hh = l >> 5, cl = l & 31;
    int myidx = idx[gn * KK + cl];
    const char* pb = (const char*)(pH + (size_t)b * NN * 256);
    int laneoff = cl * 16;

    unsigned vmax0 = 0xFC00FC00u, vmax1 = 0xFC00FC00u, vmax2 = 0xFC00FC00u, vmax3 = 0xFC00FC00u;
    unsigned vmin0 = 0x7C007C00u, vmin1 = 0x7C007C00u, vmin2 = 0x7C007C00u, vmin3 = 0x7C007C00u;

    #pragma unroll
    for (int k = 0; k < 16; k++) {
        int ja = __shfl(myidx, 2 * k, 64);
        int jb = __shfl(myidx, 2 * k + 1, 64);
        int j = hh ? jb : ja;
        uint4 raw = *(const uint4*)(pb + (((size_t)j) << 9) + laneoff);
        vmax0 = pkmax(vmax0, raw.x); vmin0 = pkmin(vmin0, raw.x);
        vmax1 = pkmax(vmax1, raw.y); vmin1 = pkmin(vmin1, raw.y);
        vmax2 = pkmax(vmax2, raw.z); vmin2 = pkmin(vmin2, raw.z);
        vmax3 = pkmax(vmax3, raw.w); vmin3 = pkmin(vmin3, raw.w);
    }
    vmax0 = pkmax(vmax0, (unsigned)__shfl_xor((int)vmax0, 32, 64));
    vmax1 = pkmax(vmax1, (unsigned)__shfl_xor((int)vmax1, 32, 64));
    vmax2 = pkmax(vmax2, (unsigned)__shfl_xor((int)vmax2, 32, 64));
    vmax3 = pkmax(vmax3, (unsigned)__shfl_xor((int)vmax3, 32, 64));
    vmin0 = pkmin(vmin0, (unsigned)__shfl_xor((int)vmin0, 32, 64));
    vmin1 = pkmin(vmin1, (unsigned)__shfl_xor((int)vmin1, 32, 64));
    vmin2 = pkmin(vmin2, (unsigned)__shfl_xor((int)vmin2, 32, 64));
    vmin3 = pkmin(vmin3, (unsigned)__shfl_xor((int)vmin3, 32, 64));

    if (hh == 0) {
        const float4* g4 = (const float4*)gd;
        float4 gA = g4[cl * 2], gB = g4[cl * 2 + 1];
        uint4 out;
        out.x = selpair(vmax0, vmin0, gA.x, gA.y);
        out.y = selpair(vmax1, vmin1, gA.z, gA.w);
        out.z = selpair(vmax2, vmin2, gB.x, gB.y);
        out.w = selpair(vmax3, vmin3, gB.z, gB.w);
        *(uint4*)((char*)pselH + (((size_t)gn) << 9) + laneoff) = out;
    } else {
        // neighbor stats: lane cl handles neighbor myidx = idx[gn*KK+cl]
        const float* rr = &R[((size_t)(b * NN) + myidx) * 8];
        float4 ra = *(const float4*)rr;
        float4 rb = *(const float4*)(rr + 4);
        float s[8] = {ra.x, ra.y, ra.z, ra.w, rb.x, rb.y, rb.z, rb.w};
        #pragma unroll
        for (int off = 16; off; off >>= 1) {
            #pragma unroll
            for (int c = 0; c < 8; c++) s[c] += __shfl_down(s[c], off, 32);
        }
        if (cl == 0) {
            float4* rp = (float4*)&Rp[(size_t)gn * 8];
            rp[0] = make_float4(s[0], s[1], s[2], s[3]);
            rp[1] = make_float4(s[4], s[5], s[6], s[7]);
        }
    }
}

// ---------------- mlp2: st2 from Rp, h2 = gelu(gn2(sel)), o = w2 @ h2 + b2, Op partials ----
// grid 512 blocks, block 256 = 4 waves; lane l owns output channel c = l; wave covers 4 n.
__global__ __launch_bounds__(256, 4)
void k_mlp2(const __half* __restrict__ pselH, const float* __restrict__ Rp,
            const float* __restrict__ w2, const float* __restrict__ b2,
            const float* __restrict__ gd, const float* __restrict__ bed,
            float* __restrict__ oraw, float* __restrict__ Op) {
    __shared__ float w2s[64 * 257];
    __shared__ float sw[4][8];
    __shared__ float sA[4][4], sB[4][4];

    int t = threadIdx.x;
    int w = t >> 6, l = t & 63;
    int b  = blockIdx.x >> 8;
    int n0 = (blockIdx.x & 255) * 16 + w * 4;

    // stage w2 -> LDS
    #pragma unroll
    for (int p = 0; p < 16; p++) {
        int i = p * 256 + t;
        int c = i >> 6, mq = i & 63;
        float4 v = ((const float4*)w2)[i];
        float* dst = &w2s[c * 257 + mq * 4];
        dst[0] = v.x; dst[1] = v.y; dst[2] = v.z; dst[3] = v.w;
    }

    // reduce Rp -> per-group stats (thread t covers 16 points)
    {
        const float4* rp = (const float4*)(Rp + (size_t)b * NN * 8);
        float s[8] = {0.f, 0.f, 0.f, 0.f, 0.f, 0.f, 0.f, 0.f};
        #pragma unroll
        for (int r = 0; r < 16; r++) {
            float4 ra = rp[(t * 16 + r) * 2];
            float4 rb = rp[(t * 16 + r) * 2 + 1];
            s[0] += ra.x; s[1] += ra.y; s[2] += ra.z; s[3] += ra.w;
            s[4] += rb.x; s[5] += rb.y; s[6] += rb.z; s[7] += rb.w;
        }
        #pragma unroll
        for (int off = 32; off; off >>= 1) {
            #pragma unroll
            for (int c = 0; c < 8; c++) s[c] += __shfl_down(s[c], off, 64);
        }
        if (l == 0) {
            #pragma unroll
            for (int c = 0; c < 8; c++) sw[w][c] = s[c];
        }
    }
    __syncthreads();

    int g = l >> 4;
    double s1 = (double)sw[0][g] + sw[1][g] + sw[2][g] + sw[3][g];
    double s2 = (double)sw[0][4 + g] + sw[1][4 + g] + sw[2][4 + g] + sw[3][4 + g];
    const double cnt2 = 64.0 * 4096.0 * 32.0;
    double m_ = s1 / cnt2;
    double v_ = s2 / cnt2 - m_ * m_;
    float mean = (float)m_;
    float rstd = rsqrtf((float)v_ + EPSF);
    float4 gd4  = ((const float4*)gd)[l];
    float4 bed4 = ((const float4*)bed)[l];
    float ax = rstd * gd4.x, ay = rstd * gd4.y, az = rstd * gd4.z, aw = rstd * gd4.w;
    float cx = bed4.x - mean * ax, cy = bed4.y - mean * ay;
    float cz = bed4.z - mean * az, cw = bed4.w - mean * aw;

    float4 h2r[4];
    #pragma unroll
    for (int j = 0; j < 4; j++) {
        uint2 raw = *(const uint2*)((const char*)pselH +
                     ((((size_t)(b * NN)) + n0 + j) << 9) + l * 8);
        float2 fa = __half22float2(*(__half2*)&raw.x);
        float2 fb = __half22float2(*(__half2*)&raw.y);
        h2r[j].x = gelu_exact(fmaf(fa.x, ax, cx));
        h2r[j].y = gelu_exact(fmaf(fa.y, ay, cy));
        h2r[j].z = gelu_exact(fmaf(fb.x, az, cz));
        h2r[j].w = gelu_exact(fmaf(fb.y, aw, cw));
    }

    const float* w2l = &w2s[l * 257];
    float acc[4] = {0.f, 0.f, 0.f, 0.f};
    #pragma unroll 8
    for (int mq = 0; mq < 64; mq++) {
        float w0  = w2l[4 * mq + 0];
        float w1_ = w2l[4 * mq + 1];
        float w2_ = w2l[4 * mq + 2];
        float w3_ = w2l[4 * mq + 3];
        #pragma unroll
        for (int j = 0; j < 4; j++) {
            acc[j] = fmaf(w0,  bcast_lane(h2r[j].x, mq), acc[j]);
            acc[j] = fmaf(w1_, bcast_lane(h2r[j].y, mq), acc[j]);
            acc[j] = fmaf(w2_, bcast_lane(h2r[j].z, mq), acc[j]);
            acc[j] = fmaf(w3_, bcast_lane(h2r[j].w, mq), acc[j]);
        }
    }

    float bias = b2[l];
    float so1 = 0.f, so2 = 0.f;
    #pragma unroll
    for (int j = 0; j < 4; j++) {
        acc[j] += bias;
        so1 += acc[j];
        so2 = fmaf(acc[j], acc[j], so2);
    }
    *(float4*)&oraw[((size_t)(b * CC) + l) * NN + n0] =
        make_float4(acc[0], acc[1], acc[2], acc[3]);

    so1 += __shfl_down(so1, 8, 16); so2 += __shfl_down(so2, 8, 16);
    so1 += __shfl_down(so1, 4, 16); so2 += __shfl_down(so2, 4, 16);
    so1 += __shfl_down(so1, 2, 16); so2 += __shfl_down(so2, 2, 16);
    so1 += __shfl_down(so1, 1, 16); so2 += __shfl_down(so2, 1, 16);
    if ((l & 15) == 0) { sA[w][l >> 4] = so1; sB[w][l >> 4] = so2; }
    __syncthreads();
    if (t < 8) {
        int is2 = t >> 2, gg = t & 3;
        float v = is2 ? (sB[0][gg] + sB[1][gg] + sB[2][gg] + sB[3][gg])
                      : (sA[0][gg] + sA[1][gg] + sA[2][gg] + sA[3][gg]);
        Op[blockIdx.x * 8 + t] = v;   // layout {s1 g0..3, s2 g0..3}
    }
}

// ---------------- final: st3 from Op, gn3 + residual (float4) ----------------
// grid 512, block 256
__global__ void k_final(const float* __restrict__ oraw, const float* __restrict__ x,
                        const float* __restrict__ g2, const float* __restrict__ be2,
                        const float* __restrict__ Op, float* __restrict__ out) {
    __shared__ float fw[4][8];
    int t = threadIdx.x;
    int i4 = blockIdx.x * 256 + t;
    int base = i4 * 4;
    int b = base >> 18;

    {
        const float4* rp = (const float4*)(Op + ((size_t)b * 256 + t) * 8);
        float4 ra = rp[0], rb = rp[1];
        float s[8] = {ra.x, ra.y, ra.z, ra.w, rb.x, rb.y, rb.z, rb.w};
        #pragma unroll
        for (int off = 32; off; off >>= 1) {
            #pragma unroll
            for (int c = 0; c < 8; c++) s[c] += __shfl_down(s[c], off, 64);
        }
        if ((t & 63) == 0) {
            #pragma unroll
            for (int c = 0; c < 8; c++) fw[t >> 6][c] = s[c];
        }
    }
    __syncthreads();

    int c = (base >> 12) & 63;
    int g = c >> 4;
    double s1 = (double)fw[0][g] + fw[1][g] + fw[2][g] + fw[3][g];
    double s2 = (double)fw[0][4 + g] + fw[1][4 + g] + fw[2][4 + g] + fw[3][4 + g];
    const double cnt = 16.0 * 4096.0;
    double mean_d = s1 / cnt;
    double var_d  = s2 / cnt - mean_d * mean_d;
    float mean = (float)mean_d;
    float rstd = rsqrtf((float)var_d + EPSF);
    float sc = rstd * g2[c];
    float ad = be2[c] - mean * sc;
    float4 o = ((const float4*)oraw)[i4];
    float4 xv = ((const float4*)x)[i4];
    float4 r;
    r.x = fmaf(o.x, sc, ad) + xv.x;
    r.y = fmaf(o.y, sc, ad) + xv.y;
    r.z = fmaf(o.z, sc, ad) + xv.z;
    r.w = fmaf(o.w, sc, ad) + xv.w;
    ((float4*)out)[i4] = r;
}

// ---------------- launch ----------------
extern "C" void kernel_launch(void* const* d_in, const int* in_sizes, int n_in,
                              void* d_out, int out_size, void* d_ws, size_t ws_size,
                              hipStream_t stream) {
    const float* x   = (const float*)d_in[0];
    const float* pos = (const float*)d_in[1];
    const float* w1  = (const float*)d_in[2];
    const float* b1  = (const float*)d_in[3];
    const float* g1  = (const float*)d_in[4];
    const float* be1 = (const float*)d_in[5];
    const float* wd  = (const float*)d_in[6];
    const float* gd  = (const float*)d_in[7];
    const float* bed = (const float*)d_in[8];
    const float* w2  = (const float*)d_in[9];
    const float* b2  = (const float*)d_in[10];
    const float* g2  = (const float*)d_in[11];
    const float* be2 = (const float*)d_in[12];
    float* out = (float*)d_out;

    char* wsb = (char*)d_ws;
    float*  h     = (float*)wsb;                   // 8 MB
    __half* pH    = (__half*)(wsb + 8388608);      // 4 MB
    __half* pselH = (__half*)(wsb + 12582912);     // 4 MB
    float*  oraw  = (float*)(wsb + 16777216);      // 2 MB
    int*    idx   = (int*)(wsb + 18874368);        // 1 MB
    float*  R     = (float*)(wsb + 19922944);      // 256 KB
    float*  Rp    = (float*)(wsb + 20185088);      // 256 KB
    float2* Mp    = (float2*)(wsb + 20447232);     // 4 KB
    float*  Op    = (float*)(wsb + 20451328);      // 16 KB

    k_mlp1<<<512, 256, 0, stream>>>(x, w1, b1, h, Mp);
    k_gn1t<<<dim3(64, 4, 2), 256, 0, stream>>>(h, g1, be1, wd, Mp, pH, R);
    k_ballq<<<2048, 256, 0, stream>>>(pos, idx);
    k_qgather<<<2048, 256, 0, stream>>>(pH, idx, R, gd, pselH, Rp);
    k_mlp2<<<512, 256, 0, stream>>>(pselH, Rp, w2, b2, gd, bed, oraw, Op);
    k_final<<<512, 256, 0, stream>>>(oraw, x, g2, be2, Op, out);
}